// Round 11
// baseline (110.759 us; speedup 1.0000x reference)
//
#include <hip/hip_runtime.h>

#define DEVFN __device__ __forceinline__

constexpr int BNN = 64 * 64 * 64;              // 262144 per output tensor
constexpr float SCALE = 0.08838834764831845f;  // 1/sqrt(128)
constexpr float NSLOPE = 0.01f;

// ---- ws layout (floats) ---- (11.93 MB, proven available R4-R10)
constexpr int OFF_WPRET = 0;       // [64][128]
constexpr int OFF_CNT   = 8192;    // grid-barrier counters (reuses dead WQT slot)
constexpr int OFF_M     = 24576;   // [128][128]  M = Wq^T Wk
constexpr int OFF_WSET  = 40960;   // [128][128]
constexpr int OFF_WSAPT = 57344;   // [96][128]
constexpr int OFF_WAVT  = 69632;   // [128][128]
constexpr int OFF_WF1T  = 86016;   // [128][64]
constexpr int OFF_E     = 98304;    // [4096][128] e row-major
constexpr int OFF_ET    = 1146880;  // [B][128][64] e feature-major
constexpr int OFF_SET   = 1671168;  // [B][128][64] se feature-major
constexpr int OFF_HA    = 2195456;  // [B][64][64]  ha = av_act @ Wf1^T
constexpr int OFF_HD    = 2719744;  // [B][64][64]

// ---- LDS region map (floats) for the fused kernel; total 19584 = 78.3 KB ----
constexpr int R_WP = 0;      // A: S [16][68]      B,C: Wp [16][68]
constexpr int R_AA = 1088;   // A: actions [16][36]
constexpr int R_AP = 1664;   // A: policies [16][36]
constexpr int R_QS = 2240;   // A: Ea/AVs -> f     B: Qs=f -> f2   C: Qs=f2   [16][132]
constexpr int R_EP = 4352;   // A: Ep   B: AV      C: Hb [16][66] @4352 + Wf2s @5408
constexpr int R_DD = 6464;   // A: Dd   B: SEr     C: Hd [64][69] @6464 (4416)
constexpr int R_ER = 8576;   // A: Er (e rows)
constexpr int R_BS = 10880;  // staging buffer, 8704 floats
constexpr int LDS_TOT = 19584;

// ============ staging: global (tight) -> LDS (padded pitch), 512 threads ============

DEVFN void st128(int tid, const float* __restrict__ src, float* __restrict__ Bs, int rows) {
  const int n4 = rows * 32;
  for (int idx = tid; idx < n4; idx += 512) {
    const int r = idx >> 5, c = idx & 31;
    *reinterpret_cast<float4*>(&Bs[r * 132 + c * 4]) =
        *reinterpret_cast<const float4*>(&src[r * 128 + c * 4]);
  }
}

// [rows][64] -> pitch 68
DEVFN void st64r(int tid, const float* __restrict__ src, float* __restrict__ Bs, int rows) {
  const int n4 = rows * 16;
  for (int idx = tid; idx < n4; idx += 512) {
    const int r = idx >> 4, c = idx & 15;
    *reinterpret_cast<float4*>(&Bs[r * 68 + c * 4]) =
        *reinterpret_cast<const float4*>(&src[r * 64 + c * 4]);
  }
}

// Coalesced feature-major writeout: src LDS [16 rows][132] -> dst global [128][64]
DEVFN void wrT(int tid, const float* __restrict__ S, float* __restrict__ dst, int rq) {
  const int fr = tid >> 2, a4 = tid & 3;
  float t[4];
#pragma unroll
  for (int i = 0; i < 4; ++i) t[i] = S[(a4 * 4 + i) * 132 + fr];
  float4 v; v.x = t[0]; v.y = t[1]; v.z = t[2]; v.w = t[3];
  *reinterpret_cast<float4*>(&dst[fr * 64 + rq * 16 + a4 * 4]) = v;
}

// ============ GEMM cores: 512 thr, 16 rows x 128 cols, 1 row x 4 cols/thread ============

DEVFN void g1(int tid, const float* __restrict__ A, int lda,
              const float* __restrict__ Bs, int K, float (&acc)[4]) {
  const int c0 = (tid & 31) * 4, rg = tid >> 5;
#pragma unroll 8
  for (int k = 0; k < K; ++k) {
    const float4 bv = *reinterpret_cast<const float4*>(&Bs[k * 132 + c0]);
    const float a = A[rg * lda + k];
    acc[0] += a * bv.x; acc[1] += a * bv.y; acc[2] += a * bv.z; acc[3] += a * bv.w;
  }
}

DEVFN void g2A(int tid, const float* __restrict__ A0, const float* __restrict__ A1,
               int lda, const float* __restrict__ Bs, int K,
               float (&a0)[4], float (&a1)[4]) {
  const int c0 = (tid & 31) * 4, rg = tid >> 5;
#pragma unroll 4
  for (int k = 0; k < K; ++k) {
    const float4 bv = *reinterpret_cast<const float4*>(&Bs[k * 132 + c0]);
    const float x = A0[rg * lda + k];
    const float y = A1[rg * lda + k];
    a0[0] += x * bv.x; a0[1] += x * bv.y; a0[2] += x * bv.z; a0[3] += x * bv.w;
    a1[0] += y * bv.x; a1[1] += y * bv.y; a1[2] += y * bv.z; a1[3] += y * bv.w;
  }
}

DEVFN void gH(int tid, const float* __restrict__ A, int lda,
              const float* __restrict__ Bs, int K, float (&acc)[2]) {
  const int c0 = (tid & 31) * 2, rg = tid >> 5;
#pragma unroll 8
  for (int k = 0; k < K; ++k) {
    const float2 bv = *reinterpret_cast<const float2*>(&Bs[k * 68 + c0]);
    const float a = A[rg * lda + k];
    acc[0] += a * bv.x; acc[1] += a * bv.y;
  }
}

DEVFN void gH2(int tid, const float* __restrict__ A0, const float* __restrict__ A1,
               int lda, const float* __restrict__ Bs, int K,
               float (&a0)[2], float (&a1)[2]) {
  const int c0 = (tid & 31) * 2, rg = tid >> 5;
#pragma unroll 4
  for (int k = 0; k < K; ++k) {
    const float2 bv = *reinterpret_cast<const float2*>(&Bs[k * 68 + c0]);
    const float x = A0[rg * lda + k];
    const float y = A1[rg * lda + k];
    a0[0] += x * bv.x; a0[1] += x * bv.y;
    a1[0] += y * bv.x; a1[1] += y * bv.y;
  }
}

template<bool ACT, bool HASB>
DEVFN void epi(int tid, const float (&acc)[4], float* __restrict__ O, int ldo,
               const float* __restrict__ bias) {
  const int c0 = (tid & 31) * 4, rg = tid >> 5;
  float t[4];
#pragma unroll
  for (int i = 0; i < 4; ++i) {
    float x = acc[i];
    if constexpr (HASB) x += bias[c0 + i];
    if constexpr (ACT) x = (x > 0.f) ? x : NSLOPE * x;
    t[i] = x;
  }
  float4 v; v.x = t[0]; v.y = t[1]; v.z = t[2]; v.w = t[3];
  *reinterpret_cast<float4*>(&O[rg * ldo + c0]) = v;
}

// ============ score (K=128) + softmax: 512 thr, 16 rows (2 rows per wave) ============

DEVFN void score_full(int tid, const float* __restrict__ Qs,
                      const float* __restrict__ Ks, float (&acc)[2]) {
  const int j = tid & 63, iw = tid >> 6;
#pragma unroll 2
  for (int kt = 0; kt < 128; kt += 8) {
    float qv[2][8];
#pragma unroll
    for (int r = 0; r < 2; ++r) {
      *reinterpret_cast<float4*>(&qv[r][0]) =
          *reinterpret_cast<const float4*>(&Qs[(iw * 2 + r) * 132 + kt]);
      *reinterpret_cast<float4*>(&qv[r][4]) =
          *reinterpret_cast<const float4*>(&Qs[(iw * 2 + r) * 132 + kt + 4]);
    }
#pragma unroll
    for (int kk = 0; kk < 8; ++kk) {
      const float kv = Ks[(kt + kk) * 68 + j];
      acc[0] += qv[0][kk] * kv;
      acc[1] += qv[1][kk] * kv;
    }
  }
}

DEVFN void softmax_write(int tid, float (&acc)[2], float* __restrict__ Wp,
                         float* __restrict__ gout) {
  const int j = tid & 63, iw = tid >> 6;
#pragma unroll
  for (int r = 0; r < 2; ++r) {
    float v = acc[r] * SCALE;
    float m = v;
#pragma unroll
    for (int off = 32; off > 0; off >>= 1) m = fmaxf(m, __shfl_xor(m, off, 64));
    const float p = __expf(v - m);
    float s = p;
#pragma unroll
    for (int off = 32; off > 0; off >>= 1) s += __shfl_xor(s, off, 64);
    const float w = p / s;
    Wp[(iw * 2 + r) * 68 + j] = w;
    gout[(iw * 2 + r) * 64 + j] = w;
  }
}

// ============ grid barrier (all 256 blocks co-resident by capacity: 78.3KB x 2 <= 160KB) ===

DEVFN void gridbar(unsigned* __restrict__ cnt, int tid) {
  __syncthreads();
  if (tid == 0) {
    __threadfence();
    atomicAdd(cnt, 1u);
    while (atomicAdd(cnt, 0u) < 256u) { __builtin_amdgcn_s_sleep(2); }
    __threadfence();
  }
  __syncthreads();
}

// ===================== the fused kernel =====================

__global__ __launch_bounds__(512) void FUSED(
    const float* __restrict__ states, const float* __restrict__ policies,
    const float* __restrict__ actions, const float* __restrict__ Wpre,
    const float* __restrict__ bpre, const float* __restrict__ Wkey,
    const float* __restrict__ Wq, const float* __restrict__ Wse,
    const float* __restrict__ bse, const float* __restrict__ Wsap,
    const float* __restrict__ bsap, const float* __restrict__ Wav,
    const float* __restrict__ Wf1, const float* __restrict__ Wf2,
    float* __restrict__ ws, float* __restrict__ out) {
  __shared__ float L[LDS_TOT];
  const int tid = threadIdx.x;
  const int bid = blockIdx.x;
  const int wid = ((bid & 7) << 5) | (bid >> 3);   // XCD-affinity swizzle
  const int b = wid >> 2, rq = wid & 3;
  const int r0g = b * 64 + rq * 16;
  unsigned* cnt = (unsigned*)(ws + OFF_CNT);

  // ---------- phase 0: weight transposes (whole grid) ----------
  {
    const int gt = bid * 512 + tid;
    if (gt < 8192) {                       // Wpre [128][64] -> WPRET [64][128]
      const int c = gt >> 6, k = gt & 63;
      ws[OFF_WPRET + k * 128 + c] = Wpre[gt];
    } else if (gt < 24576) {               // Wse [128][128] -> WSET
      const int i = gt - 8192, c = i >> 7, k = i & 127;
      ws[OFF_WSET + k * 128 + c] = Wse[i];
    } else if (gt < 36864) {               // Wsap [128][96] -> WSAPT [96][128]
      const int i = gt - 24576, c = i / 96, k = i - c * 96;
      ws[OFF_WSAPT + k * 128 + c] = Wsap[i];
    } else if (gt < 53248) {               // Wav [128][128] -> WAVT
      const int i = gt - 36864, c = i >> 7, k = i & 127;
      ws[OFF_WAVT + k * 128 + c] = Wav[i];
    } else if (gt < 61440) {               // Wf1 [64][128] -> WF1T [128][64]
      const int i = gt - 53248, c = i >> 7, k = i & 127;
      ws[OFF_WF1T + k * 64 + c] = Wf1[i];
    }
  }
  // blocks 0..7: M = Wq^T @ Wk (reads raw inputs only)
  if (bid < 8) {
    const int r0 = bid * 16;
    float* As = L + R_QS;
    float* Bs = L + R_BS;
    for (int idx = tid; idx < 2048; idx += 512) {
      const int r = idx & 15, o = idx >> 4;
      As[r * 132 + o] = Wq[o * 128 + r0 + r];
    }
    const int c0 = (tid & 31) * 4, rg = tid >> 5;
    float acc[4] = {};
    for (int h = 0; h < 2; ++h) {
      __syncthreads();
      st128(tid, Wkey + h * 8192, Bs, 64);
      __syncthreads();
#pragma unroll 8
      for (int k = 0; k < 64; ++k) {
        const float4 bv = *reinterpret_cast<const float4*>(&Bs[k * 132 + c0]);
        const float a = As[rg * 132 + h * 64 + k];
        acc[0] += a * bv.x; acc[1] += a * bv.y; acc[2] += a * bv.z; acc[3] += a * bv.w;
      }
    }
    float4 v; v.x = acc[0]; v.y = acc[1]; v.z = acc[2]; v.w = acc[3];
    *reinterpret_cast<float4*>(&ws[OFF_M + (r0 + rg) * 128 + c0]) = v;
  }
  gridbar(cnt + 0, tid);

  // ---------- phase A (= P1): per-16-row prep; f stays in LDS ----------
  {
    float* S  = L + R_WP;
    float* Aa = L + R_AA;
    float* Ap = L + R_AP;
    float* Ea = L + R_QS;   // Esap_act -> AVs -> (later) f
    float* Ep = L + R_EP;
    float* Dd = L + R_DD;
    float* Er = L + R_ER;
    float* Bs = L + R_BS;

    for (int idx = tid; idx < 1024; idx += 512) {
      const int r = idx >> 6, c = idx & 63;
      S[r * 68 + c] = states[(r0g + r) * 64 + c];
    }
    {
      const int r = tid >> 5, c = tid & 31;
      Aa[r * 36 + c] = actions[(r0g + r) * 32 + c];
      Ap[r * 36 + c] = policies[(r0g + r) * 32 + c];
    }
    st128(tid, ws + OFF_WSAPT, Bs, 64);
    __syncthreads();
    float cm[4] = {};
    g1(tid, S, 68, Bs, 64, cm);
    __syncthreads();
    st128(tid, ws + OFF_WSAPT + 8192, Bs, 32);
    __syncthreads();
    float aa[4] = {cm[0], cm[1], cm[2], cm[3]};
    float ap[4] = {cm[0], cm[1], cm[2], cm[3]};
    g2A(tid, Aa, Ap, 36, Bs, 32, aa, ap);
    epi<true, true>(tid, aa, Ea, 132, bsap);
    epi<true, true>(tid, ap, Ep, 132, bsap);
    __syncthreads();
    for (int idx = tid; idx < 2048; idx += 512) {
      const int r = idx >> 7, c = idx & 127;
      Ep[r * 132 + c] -= Ea[r * 132 + c];
    }
    __syncthreads();
    // av_act / delta (K=128)
    st128(tid, ws + OFF_WAVT, Bs, 64);
    __syncthreads();
    float av[4] = {}, dl[4] = {};
    g2A(tid, Ea, Ep, 132, Bs, 64, av, dl);
    __syncthreads();
    st128(tid, ws + OFF_WAVT + 8192, Bs, 64);
    __syncthreads();
    g2A(tid, Ea + 64, Ep + 64, 132, Bs, 64, av, dl);
    __syncthreads();
    epi<false, false>(tid, av, Ea, 132, nullptr);  // Ea := AVs
    epi<false, false>(tid, dl, Dd, 132, nullptr);
    __syncthreads();
    // hd = delta @ Wf1^T ; ha = av_act @ Wf1^T
    st64r(tid, ws + OFF_WF1T, Bs, 64);
    __syncthreads();
    float ah[2] = {}, aha[2] = {};
    gH2(tid, Dd, Ea, 132, Bs, 64, ah, aha);
    __syncthreads();
    st64r(tid, ws + OFF_WF1T + 4096, Bs, 64);
    __syncthreads();
    gH2(tid, Dd + 64, Ea + 64, 132, Bs, 64, ah, aha);
    {
      const int c0 = (tid & 31) * 2, rg = tid >> 5;
      float2 vh; vh.x = ah[0]; vh.y = ah[1];
      float2 va; va.x = aha[0]; va.y = aha[1];
      *reinterpret_cast<float2*>(&ws[OFF_HD + (r0g + rg) * 64 + c0]) = vh;
      *reinterpret_cast<float2*>(&ws[OFF_HA + (r0g + rg) * 64 + c0]) = va;
    }
    __syncthreads();
    // e = lrelu(states @ Wpre^T + b) -> Er + ws.E
    st128(tid, ws + OFF_WPRET, Bs, 64);
    __syncthreads();
    {
      float ae[4] = {};
      g1(tid, S, 68, Bs, 64, ae);
      const int c0 = (tid & 31) * 4, rg = tid >> 5;
      float t[4];
#pragma unroll
      for (int i = 0; i < 4; ++i) {
        float x = ae[i] + bpre[c0 + i];
        t[i] = (x > 0.f) ? x : NSLOPE * x;
      }
      float4 v; v.x = t[0]; v.y = t[1]; v.z = t[2]; v.w = t[3];
      *reinterpret_cast<float4*>(&Er[rg * 132 + c0]) = v;
      *reinterpret_cast<float4*>(&ws[OFF_E + (r0g + rg) * 128 + c0]) = v;
    }
    __syncthreads();
    wrT(tid, Er, ws + OFF_ET + b * 8192, rq);
    st128(tid, ws + OFF_M, Bs, 64);
    __syncthreads();
    // f = e @ M -> LDS (R_QS); never goes to global
    float af[4] = {};
    g1(tid, Er, 132, Bs, 64, af);
    __syncthreads();
    st128(tid, ws + OFF_M + 8192, Bs, 64);
    __syncthreads();
    g1(tid, Er + 64, 132, Bs, 64, af);
    epi<false, false>(tid, af, L + R_QS, 132, nullptr);
  }
  gridbar(cnt + 1, tid);

  // ---------- phase B (= P3): score1 -> w_pre ; av_pre ; se ; f2 (to LDS) ----------
  {
    float* Qs  = L + R_QS;
    float* Wp  = L + R_WP;
    float* AV  = L + R_EP;
    float* SEr = L + R_DD;
    float* Bs  = L + R_BS;

    st64r(tid, ws + OFF_ET + b * 8192, Bs, 128);
    __syncthreads();
    float sc[2] = {};
    score_full(tid, Qs, Bs, sc);
    softmax_write(tid, sc, Wp, out + BNN + b * 4096 + rq * 1024);
    __syncthreads();
    // av_pre = w_pre @ e[b]
    st128(tid, ws + OFF_E + b * 8192, Bs, 64);
    __syncthreads();
    {
      float a[4] = {};
      g1(tid, Wp, 68, Bs, 64, a);
      epi<false, false>(tid, a, AV, 132, nullptr);
    }
    __syncthreads();
    // se = lrelu(av_pre @ Wse^T + b_se)
    st128(tid, ws + OFF_WSET, Bs, 64);
    __syncthreads();
    float as[4] = {};
    g1(tid, AV, 132, Bs, 64, as);
    __syncthreads();
    st128(tid, ws + OFF_WSET + 8192, Bs, 64);
    __syncthreads();
    g1(tid, AV + 64, 132, Bs, 64, as);
    {
      const int c0 = (tid & 31) * 4, rg = tid >> 5;
      float t[4];
#pragma unroll
      for (int i = 0; i < 4; ++i) {
        float x = as[i] + bse[c0 + i];
        t[i] = (x > 0.f) ? x : NSLOPE * x;
      }
      float4 v; v.x = t[0]; v.y = t[1]; v.z = t[2]; v.w = t[3];
      *reinterpret_cast<float4*>(&SEr[rg * 132 + c0]) = v;
    }
    __syncthreads();
    wrT(tid, SEr, ws + OFF_SET + b * 8192, rq);
    st128(tid, ws + OFF_M, Bs, 64);
    __syncthreads();
    // f2 = se @ M -> LDS (R_QS)
    float af[4] = {};
    g1(tid, SEr, 132, Bs, 64, af);
    __syncthreads();
    st128(tid, ws + OFF_M + 8192, Bs, 64);
    __syncthreads();
    g1(tid, SEr + 64, 132, Bs, 64, af);
    epi<false, false>(tid, af, Qs, 132, nullptr);
  }
  gridbar(cnt + 2, tid);

  // ---------- phase C (= P4): score2 -> w ; h_base = w @ ha ; head ----------
  {
    float* Qs   = L + R_QS;
    float* Wp   = L + R_WP;
    float* Hb   = L + R_EP;          // [16][66]
    float* Wf2s = L + R_EP + 1056;
    float* Hd   = L + R_DD;          // [64][69]
    float* Bs   = L + R_BS;

    for (int idx = tid; idx < 4096; idx += 512)
      Hd[(idx >> 6) * 69 + (idx & 63)] = ws[OFF_HD + b * 4096 + idx];
    if (tid < 64) Wf2s[tid] = Wf2[tid];
    st64r(tid, ws + OFF_SET + b * 8192, Bs, 128);
    __syncthreads();
    float sc[2] = {};
    score_full(tid, Qs, Bs, sc);
    softmax_write(tid, sc, Wp, out + 2 * BNN + b * 4096 + rq * 1024);
    __syncthreads();
    // h_base = w @ ha[b]
    st64r(tid, ws + OFF_HA + b * 4096, Bs, 64);
    __syncthreads();
    float ah[2] = {};
    gH(tid, Wp, 68, Bs, 64, ah);
    {
      const int c0 = (tid & 31) * 2, rg = tid >> 5;
      float2 v; v.x = ah[0]; v.y = ah[1];
      *reinterpret_cast<float2*>(&Hb[rg * 66 + c0]) = v;
    }
    __syncthreads();
    // head: value[i][j] = sum_f lrelu(Hb[i,f] + w[i,j]*Hd[j,f]) * Wf2[f]
    const int j = tid & 63, iw = tid >> 6;
    float wv[2], a2[2] = {0.f, 0.f};
#pragma unroll
    for (int r = 0; r < 2; ++r) wv[r] = Wp[(iw * 2 + r) * 68 + j];
    for (int f = 0; f < 64; ++f) {
      const float hdv = Hd[j * 69 + f];
      const float wf = Wf2s[f];
#pragma unroll
      for (int r = 0; r < 2; ++r) {
        float t = Hb[(iw * 2 + r) * 66 + f] + wv[r] * hdv;
        t = (t > 0.f) ? t : NSLOPE * t;
        a2[r] += t * wf;
      }
    }
#pragma unroll
    for (int r = 0; r < 2; ++r)
      out[(r0g + iw * 2 + r) * 64 + j] = a2[r];
  }
}

extern "C" void kernel_launch(void* const* d_in, const int* in_sizes, int n_in,
                              void* d_out, int out_size, void* d_ws, size_t ws_size,
                              hipStream_t stream) {
  const float* states   = (const float*)d_in[0];
  const float* policies = (const float*)d_in[1];
  const float* actions  = (const float*)d_in[2];
  const float* W_se_pre = (const float*)d_in[3];
  const float* b_se_pre = (const float*)d_in[4];
  const float* W_key    = (const float*)d_in[5];
  const float* W_query  = (const float*)d_in[6];
  const float* W_se     = (const float*)d_in[7];
  const float* b_se     = (const float*)d_in[8];
  const float* W_sap    = (const float*)d_in[9];
  const float* b_sap    = (const float*)d_in[10];
  const float* W_av     = (const float*)d_in[11];
  const float* W_f1     = (const float*)d_in[12];
  const float* W_f2     = (const float*)d_in[13];
  float* out = (float*)d_out;
  float* ws  = (float*)d_ws;

  // zero the grid-barrier counters (deterministic per call)
  hipMemsetAsync(ws + OFF_CNT, 0, 16, stream);
  FUSED<<<dim3(256), dim3(512), 0, stream>>>(
      states, policies, actions, W_se_pre, b_se_pre, W_key, W_query, W_se, b_se,
      W_sap, b_sap, W_av, W_f1, W_f2, ws, out);
}

// Round 12
// 83.055 us; speedup vs baseline: 1.3336x; 1.3336x over previous
//
#include <hip/hip_runtime.h>

#define DEVFN __device__ __forceinline__

constexpr int BNN = 64 * 64 * 64;              // 262144 per output tensor
constexpr float SCALE = 0.08838834764831845f;  // 1/sqrt(128)
constexpr float NSLOPE = 0.01f;

// ---- ws layout (floats) ---- (11.93 MB, proven)
constexpr int OFF_WPRET = 0;       // [64][128]
constexpr int OFF_CNT   = 8192;    // per-batch group-barrier counters (64 x u32)
constexpr int OFF_M     = 24576;   // [128][128]  M = Wq^T Wk
constexpr int OFF_WSET  = 40960;   // [128][128]
constexpr int OFF_WSAPT = 57344;   // [96][128]
constexpr int OFF_WAVT  = 69632;   // [128][128]
constexpr int OFF_WF1T  = 86016;   // [128][64]
constexpr int OFF_E     = 98304;    // [4096][128] e row-major
constexpr int OFF_ET    = 1146880;  // [B][128][64] e feature-major
constexpr int OFF_SET   = 1671168;  // [B][128][64] se feature-major
constexpr int OFF_HA    = 2195456;  // [B][64][64]
constexpr int OFF_HD    = 2719744;  // [B][64][64]

// ============ staging: global (tight) -> LDS (padded pitch), 512 threads ============

DEVFN void st128(int tid, const float* __restrict__ src, float* __restrict__ Bs, int rows) {
  const int n4 = rows * 32;
  for (int idx = tid; idx < n4; idx += 512) {
    const int r = idx >> 5, c = idx & 31;
    *reinterpret_cast<float4*>(&Bs[r * 132 + c * 4]) =
        *reinterpret_cast<const float4*>(&src[r * 128 + c * 4]);
  }
}

// [rows][64] -> pitch 68
DEVFN void st64r(int tid, const float* __restrict__ src, float* __restrict__ Bs, int rows) {
  const int n4 = rows * 16;
  for (int idx = tid; idx < n4; idx += 512) {
    const int r = idx >> 4, c = idx & 15;
    *reinterpret_cast<float4*>(&Bs[r * 68 + c * 4]) =
        *reinterpret_cast<const float4*>(&src[r * 64 + c * 4]);
  }
}

// Coalesced feature-major writeout: src LDS [16 rows][132] -> dst global [128][64]
DEVFN void wrT(int tid, const float* __restrict__ S, float* __restrict__ dst, int rq) {
  const int fr = tid >> 2, a4 = tid & 3;
  float t[4];
#pragma unroll
  for (int i = 0; i < 4; ++i) t[i] = S[(a4 * 4 + i) * 132 + fr];
  float4 v; v.x = t[0]; v.y = t[1]; v.z = t[2]; v.w = t[3];
  *reinterpret_cast<float4*>(&dst[fr * 64 + rq * 16 + a4 * 4]) = v;
}

// ============ GEMM cores: 512 thr, 16 rows x 128 cols, 1 row x 4 cols/thread ============

DEVFN void g1(int tid, const float* __restrict__ A, int lda,
              const float* __restrict__ Bs, int K, float (&acc)[4]) {
  const int c0 = (tid & 31) * 4, rg = tid >> 5;
#pragma unroll 8
  for (int k = 0; k < K; ++k) {
    const float4 bv = *reinterpret_cast<const float4*>(&Bs[k * 132 + c0]);
    const float a = A[rg * lda + k];
    acc[0] += a * bv.x; acc[1] += a * bv.y; acc[2] += a * bv.z; acc[3] += a * bv.w;
  }
}

DEVFN void g2A(int tid, const float* __restrict__ A0, const float* __restrict__ A1,
               int lda, const float* __restrict__ Bs, int K,
               float (&a0)[4], float (&a1)[4]) {
  const int c0 = (tid & 31) * 4, rg = tid >> 5;
#pragma unroll 4
  for (int k = 0; k < K; ++k) {
    const float4 bv = *reinterpret_cast<const float4*>(&Bs[k * 132 + c0]);
    const float x = A0[rg * lda + k];
    const float y = A1[rg * lda + k];
    a0[0] += x * bv.x; a0[1] += x * bv.y; a0[2] += x * bv.z; a0[3] += x * bv.w;
    a1[0] += y * bv.x; a1[1] += y * bv.y; a1[2] += y * bv.z; a1[3] += y * bv.w;
  }
}

DEVFN void gH(int tid, const float* __restrict__ A, int lda,
              const float* __restrict__ Bs, int K, float (&acc)[2]) {
  const int c0 = (tid & 31) * 2, rg = tid >> 5;
#pragma unroll 8
  for (int k = 0; k < K; ++k) {
    const float2 bv = *reinterpret_cast<const float2*>(&Bs[k * 68 + c0]);
    const float a = A[rg * lda + k];
    acc[0] += a * bv.x; acc[1] += a * bv.y;
  }
}

DEVFN void gH2(int tid, const float* __restrict__ A0, const float* __restrict__ A1,
               int lda, const float* __restrict__ Bs, int K,
               float (&a0)[2], float (&a1)[2]) {
  const int c0 = (tid & 31) * 2, rg = tid >> 5;
#pragma unroll 4
  for (int k = 0; k < K; ++k) {
    const float2 bv = *reinterpret_cast<const float2*>(&Bs[k * 68 + c0]);
    const float x = A0[rg * lda + k];
    const float y = A1[rg * lda + k];
    a0[0] += x * bv.x; a0[1] += x * bv.y;
    a1[0] += y * bv.x; a1[1] += y * bv.y;
  }
}

template<bool ACT, bool HASB>
DEVFN void epi(int tid, const float (&acc)[4], float* __restrict__ O, int ldo,
               const float* __restrict__ bias) {
  const int c0 = (tid & 31) * 4, rg = tid >> 5;
  float t[4];
#pragma unroll
  for (int i = 0; i < 4; ++i) {
    float x = acc[i];
    if constexpr (HASB) x += bias[c0 + i];
    if constexpr (ACT) x = (x > 0.f) ? x : NSLOPE * x;
    t[i] = x;
  }
  float4 v; v.x = t[0]; v.y = t[1]; v.z = t[2]; v.w = t[3];
  *reinterpret_cast<float4*>(&O[rg * ldo + c0]) = v;
}

// ============ score (K=128) + softmax: 512 thr, 16 rows (2 rows per wave) ============

DEVFN void score_full(int tid, const float* __restrict__ Qs,
                      const float* __restrict__ Ks, float (&acc)[2]) {
  const int j = tid & 63, iw = tid >> 6;
#pragma unroll 2
  for (int kt = 0; kt < 128; kt += 8) {
    float qv[2][8];
#pragma unroll
    for (int r = 0; r < 2; ++r) {
      *reinterpret_cast<float4*>(&qv[r][0]) =
          *reinterpret_cast<const float4*>(&Qs[(iw * 2 + r) * 132 + kt]);
      *reinterpret_cast<float4*>(&qv[r][4]) =
          *reinterpret_cast<const float4*>(&Qs[(iw * 2 + r) * 132 + kt + 4]);
    }
#pragma unroll
    for (int kk = 0; kk < 8; ++kk) {
      const float kv = Ks[(kt + kk) * 68 + j];
      acc[0] += qv[0][kk] * kv;
      acc[1] += qv[1][kk] * kv;
    }
  }
}

DEVFN void softmax_write(int tid, float (&acc)[2], float* __restrict__ Wp,
                         float* __restrict__ gout) {
  const int j = tid & 63, iw = tid >> 6;
#pragma unroll
  for (int r = 0; r < 2; ++r) {
    float v = acc[r] * SCALE;
    float m = v;
#pragma unroll
    for (int off = 32; off > 0; off >>= 1) m = fmaxf(m, __shfl_xor(m, off, 64));
    const float p = __expf(v - m);
    float s = p;
#pragma unroll
    for (int off = 32; off > 0; off >>= 1) s += __shfl_xor(s, off, 64);
    const float w = p / s;
    Wp[(iw * 2 + r) * 68 + j] = w;
    gout[(iw * 2 + r) * 64 + j] = w;
  }
}

// ============ per-batch group barrier (4 blocks of one batch; same XCD via swizzle) ====

DEVFN void groupbar(unsigned* __restrict__ cnt, int tid, unsigned target) {
  __syncthreads();
  if (tid == 0) {
    __threadfence();
    atomicAdd(cnt, 1u);
    while (__hip_atomic_load(cnt, __ATOMIC_ACQUIRE, __HIP_MEMORY_SCOPE_AGENT) < target) {
      __builtin_amdgcn_s_sleep(8);
    }
    __threadfence();
  }
  __syncthreads();
}

// ===================== kernel 1: weight transposes + M = Wq^T Wk =====================

__global__ __launch_bounds__(512) void WPREP(const float* __restrict__ Wpre,
                                             const float* __restrict__ Wq,
                                             const float* __restrict__ Wkey,
                                             const float* __restrict__ Wse,
                                             const float* __restrict__ Wsap,
                                             const float* __restrict__ Wav,
                                             const float* __restrict__ Wf1,
                                             float* __restrict__ ws) {
  __shared__ float As[16 * 132];
  __shared__ float Bs[64 * 132];
  const int tid = threadIdx.x, bid = blockIdx.x;
  if (bid < 120) {
    const int gt = bid * 512 + tid;
    if (gt < 8192) {                       // Wpre [128][64] -> WPRET [64][128]
      const int c = gt >> 6, k = gt & 63;
      ws[OFF_WPRET + k * 128 + c] = Wpre[gt];
    } else if (gt < 24576) {               // Wse -> WSET
      const int i = gt - 8192, c = i >> 7, k = i & 127;
      ws[OFF_WSET + k * 128 + c] = Wse[i];
    } else if (gt < 36864) {               // Wsap [128][96] -> WSAPT [96][128]
      const int i = gt - 24576, c = i / 96, k = i - c * 96;
      ws[OFF_WSAPT + k * 128 + c] = Wsap[i];
    } else if (gt < 53248) {               // Wav -> WAVT
      const int i = gt - 36864, c = i >> 7, k = i & 127;
      ws[OFF_WAVT + k * 128 + c] = Wav[i];
    } else if (gt < 61440) {               // Wf1 [64][128] -> WF1T [128][64]
      const int i = gt - 53248, c = i >> 7, k = i & 127;
      ws[OFF_WF1T + k * 64 + c] = Wf1[i];
    }
  } else {
    const int r0 = (bid - 120) * 16;
    for (int idx = tid; idx < 2048; idx += 512) {
      const int r = idx & 15, o = idx >> 4;
      As[r * 132 + o] = Wq[o * 128 + r0 + r];
    }
    const int c0 = (tid & 31) * 4, rg = tid >> 5;
    float acc[4] = {};
    for (int h = 0; h < 2; ++h) {
      __syncthreads();
      st128(tid, Wkey + h * 8192, Bs, 64);
      __syncthreads();
#pragma unroll 8
      for (int k = 0; k < 64; ++k) {
        const float4 bv = *reinterpret_cast<const float4*>(&Bs[k * 132 + c0]);
        const float a = As[rg * 132 + h * 64 + k];
        acc[0] += a * bv.x; acc[1] += a * bv.y; acc[2] += a * bv.z; acc[3] += a * bv.w;
      }
    }
    float4 v; v.x = acc[0]; v.y = acc[1]; v.z = acc[2]; v.w = acc[3];
    *reinterpret_cast<float4*>(&ws[OFF_M + (r0 + rg) * 128 + c0]) = v;
  }
}

// ===================== kernel 2: fused A/B/C with per-batch barriers =====================

__global__ __launch_bounds__(512) void FUSED3(
    const float* __restrict__ states, const float* __restrict__ policies,
    const float* __restrict__ actions, const float* __restrict__ bpre,
    const float* __restrict__ bse, const float* __restrict__ bsap,
    const float* __restrict__ Wf2, float* __restrict__ ws, float* __restrict__ out) {
  // named arrays -> compiler-visible non-aliasing (R11's single-L killed this)
  __shared__ float WpS[16 * 68];    // A: S         B/C: Wp
  __shared__ float AaS[16 * 36];    // A only
  __shared__ float ApS[16 * 36];    // A only
  __shared__ float FQ[16 * 132];    // A: Ea/AVs -> f   B: Qs -> f2   C: Qs
  __shared__ float EpS[16 * 132];   // A: Ep   B: AV   C: Hb [16][66] + Wf2s
  __shared__ float DdS[16 * 132];   // A: Dd   B: SEr
  __shared__ float HdS[64 * 69];    // A: Er (first 2112)   C: Hd
  __shared__ float Bs[8704];        // staging
  const int tid = threadIdx.x;
  const int bid = blockIdx.x;
  const int wid = ((bid & 7) << 5) | (bid >> 3);   // XCD swizzle: batch-group on one XCD
  const int b = wid >> 2, rq = wid & 3;
  const int r0g = b * 64 + rq * 16;
  unsigned* cnt = (unsigned*)(ws + OFF_CNT) + b;

  // ---------- phase A: prep; f stays in LDS ----------
  {
    float* S  = WpS;
    float* Ea = FQ;
    float* Er = HdS;
    for (int idx = tid; idx < 1024; idx += 512) {
      const int r = idx >> 6, c = idx & 63;
      S[r * 68 + c] = states[(r0g + r) * 64 + c];
    }
    {
      const int r = tid >> 5, c = tid & 31;
      AaS[r * 36 + c] = actions[(r0g + r) * 32 + c];
      ApS[r * 36 + c] = policies[(r0g + r) * 32 + c];
    }
    st128(tid, ws + OFF_WSAPT, Bs, 64);
    __syncthreads();
    float cm[4] = {};
    g1(tid, S, 68, Bs, 64, cm);
    __syncthreads();
    st128(tid, ws + OFF_WSAPT + 8192, Bs, 32);
    __syncthreads();
    float aa[4] = {cm[0], cm[1], cm[2], cm[3]};
    float ap[4] = {cm[0], cm[1], cm[2], cm[3]};
    g2A(tid, AaS, ApS, 36, Bs, 32, aa, ap);
    epi<true, true>(tid, aa, Ea, 132, bsap);
    epi<true, true>(tid, ap, EpS, 132, bsap);
    __syncthreads();
    for (int idx = tid; idx < 2048; idx += 512) {
      const int r = idx >> 7, c = idx & 127;
      EpS[r * 132 + c] -= Ea[r * 132 + c];
    }
    __syncthreads();
    // av_act / delta (K=128)
    st128(tid, ws + OFF_WAVT, Bs, 64);
    __syncthreads();
    float av[4] = {}, dl[4] = {};
    g2A(tid, Ea, EpS, 132, Bs, 64, av, dl);
    __syncthreads();
    st128(tid, ws + OFF_WAVT + 8192, Bs, 64);
    __syncthreads();
    g2A(tid, Ea + 64, EpS + 64, 132, Bs, 64, av, dl);
    __syncthreads();
    epi<false, false>(tid, av, Ea, 132, nullptr);   // Ea := AVs
    epi<false, false>(tid, dl, DdS, 132, nullptr);
    __syncthreads();
    // hd = delta @ Wf1^T ; ha = av_act @ Wf1^T
    st64r(tid, ws + OFF_WF1T, Bs, 64);
    __syncthreads();
    float ah[2] = {}, aha[2] = {};
    gH2(tid, DdS, Ea, 132, Bs, 64, ah, aha);
    __syncthreads();
    st64r(tid, ws + OFF_WF1T + 4096, Bs, 64);
    __syncthreads();
    gH2(tid, DdS + 64, Ea + 64, 132, Bs, 64, ah, aha);
    {
      const int c0 = (tid & 31) * 2, rg = tid >> 5;
      float2 vh; vh.x = ah[0]; vh.y = ah[1];
      float2 va; va.x = aha[0]; va.y = aha[1];
      *reinterpret_cast<float2*>(&ws[OFF_HD + (r0g + rg) * 64 + c0]) = vh;
      *reinterpret_cast<float2*>(&ws[OFF_HA + (r0g + rg) * 64 + c0]) = va;
    }
    __syncthreads();
    // e = lrelu(states @ Wpre^T + b) -> Er + ws.E
    st128(tid, ws + OFF_WPRET, Bs, 64);
    __syncthreads();
    {
      float ae[4] = {};
      g1(tid, S, 68, Bs, 64, ae);
      const int c0 = (tid & 31) * 4, rg = tid >> 5;
      float t[4];
#pragma unroll
      for (int i = 0; i < 4; ++i) {
        float x = ae[i] + bpre[c0 + i];
        t[i] = (x > 0.f) ? x : NSLOPE * x;
      }
      float4 v; v.x = t[0]; v.y = t[1]; v.z = t[2]; v.w = t[3];
      *reinterpret_cast<float4*>(&Er[rg * 132 + c0]) = v;
      *reinterpret_cast<float4*>(&ws[OFF_E + (r0g + rg) * 128 + c0]) = v;
    }
    __syncthreads();
    wrT(tid, Er, ws + OFF_ET + b * 8192, rq);
    st128(tid, ws + OFF_M, Bs, 64);
    __syncthreads();
    // f = e @ M -> FQ (never to global)
    float af[4] = {};
    g1(tid, Er, 132, Bs, 64, af);
    __syncthreads();
    st128(tid, ws + OFF_M + 8192, Bs, 64);
    __syncthreads();
    g1(tid, Er + 64, 132, Bs, 64, af);
    epi<false, false>(tid, af, FQ, 132, nullptr);
  }
  groupbar(cnt, tid, 4u);

  // ---------- phase B: score1 -> w_pre ; av_pre ; se ; f2 (to LDS) ----------
  {
    float* Wp  = WpS;
    float* AV  = EpS;
    float* SEr = DdS;

    st64r(tid, ws + OFF_ET + b * 8192, Bs, 128);
    __syncthreads();
    float sc[2] = {};
    score_full(tid, FQ, Bs, sc);
    softmax_write(tid, sc, Wp, out + BNN + b * 4096 + rq * 1024);
    __syncthreads();
    // av_pre = w_pre @ e[b]
    st128(tid, ws + OFF_E + b * 8192, Bs, 64);
    __syncthreads();
    {
      float a[4] = {};
      g1(tid, Wp, 68, Bs, 64, a);
      epi<false, false>(tid, a, AV, 132, nullptr);
    }
    __syncthreads();
    // se = lrelu(av_pre @ Wse^T + b_se)
    st128(tid, ws + OFF_WSET, Bs, 64);
    __syncthreads();
    float as[4] = {};
    g1(tid, AV, 132, Bs, 64, as);
    __syncthreads();
    st128(tid, ws + OFF_WSET + 8192, Bs, 64);
    __syncthreads();
    g1(tid, AV + 64, 132, Bs, 64, as);
    {
      const int c0 = (tid & 31) * 4, rg = tid >> 5;
      float t[4];
#pragma unroll
      for (int i = 0; i < 4; ++i) {
        float x = as[i] + bse[c0 + i];
        t[i] = (x > 0.f) ? x : NSLOPE * x;
      }
      float4 v; v.x = t[0]; v.y = t[1]; v.z = t[2]; v.w = t[3];
      *reinterpret_cast<float4*>(&SEr[rg * 132 + c0]) = v;
    }
    __syncthreads();
    wrT(tid, SEr, ws + OFF_SET + b * 8192, rq);
    st128(tid, ws + OFF_M, Bs, 64);
    __syncthreads();
    // f2 = se @ M -> FQ
    float af[4] = {};
    g1(tid, SEr, 132, Bs, 64, af);
    __syncthreads();
    st128(tid, ws + OFF_M + 8192, Bs, 64);
    __syncthreads();
    g1(tid, SEr + 64, 132, Bs, 64, af);
    epi<false, false>(tid, af, FQ, 132, nullptr);
  }
  groupbar(cnt, tid, 8u);

  // ---------- phase C: score2 -> w ; h_base = w @ ha ; head ----------
  {
    float* Wp   = WpS;
    float* Hb   = EpS;               // [16][66]
    float* Wf2s = EpS + 1056;
    float* Hd   = HdS;               // [64][69]

    for (int idx = tid; idx < 4096; idx += 512)
      Hd[(idx >> 6) * 69 + (idx & 63)] = ws[OFF_HD + b * 4096 + idx];
    if (tid < 64) Wf2s[tid] = Wf2[tid];
    st64r(tid, ws + OFF_SET + b * 8192, Bs, 128);
    __syncthreads();
    float sc[2] = {};
    score_full(tid, FQ, Bs, sc);
    softmax_write(tid, sc, Wp, out + 2 * BNN + b * 4096 + rq * 1024);
    __syncthreads();
    // h_base = w @ ha[b]
    st64r(tid, ws + OFF_HA + b * 4096, Bs, 64);
    __syncthreads();
    float ah[2] = {};
    gH(tid, Wp, 68, Bs, 64, ah);
    {
      const int c0 = (tid & 31) * 2, rg = tid >> 5;
      float2 v; v.x = ah[0]; v.y = ah[1];
      *reinterpret_cast<float2*>(&Hb[rg * 66 + c0]) = v;
    }
    __syncthreads();
    // head
    const int j = tid & 63, iw = tid >> 6;
    float wv[2], a2[2] = {0.f, 0.f};
#pragma unroll
    for (int r = 0; r < 2; ++r) wv[r] = Wp[(iw * 2 + r) * 68 + j];
    for (int f = 0; f < 64; ++f) {
      const float hdv = Hd[j * 69 + f];
      const float wf = Wf2s[f];
#pragma unroll
      for (int r = 0; r < 2; ++r) {
        float t = Hb[(iw * 2 + r) * 66 + f] + wv[r] * hdv;
        t = (t > 0.f) ? t : NSLOPE * t;
        a2[r] += t * wf;
      }
    }
#pragma unroll
    for (int r = 0; r < 2; ++r)
      out[(r0g + iw * 2 + r) * 64 + j] = a2[r];
  }
}

extern "C" void kernel_launch(void* const* d_in, const int* in_sizes, int n_in,
                              void* d_out, int out_size, void* d_ws, size_t ws_size,
                              hipStream_t stream) {
  const float* states   = (const float*)d_in[0];
  const float* policies = (const float*)d_in[1];
  const float* actions  = (const float*)d_in[2];
  const float* W_se_pre = (const float*)d_in[3];
  const float* b_se_pre = (const float*)d_in[4];
  const float* W_key    = (const float*)d_in[5];
  const float* W_query  = (const float*)d_in[6];
  const float* W_se     = (const float*)d_in[7];
  const float* b_se     = (const float*)d_in[8];
  const float* W_sap    = (const float*)d_in[9];
  const float* b_sap    = (const float*)d_in[10];
  const float* W_av     = (const float*)d_in[11];
  const float* W_f1     = (const float*)d_in[12];
  const float* W_f2     = (const float*)d_in[13];
  float* out = (float*)d_out;
  float* ws  = (float*)d_ws;

  // zero per-batch barrier counters (deterministic per call)
  hipMemsetAsync(ws + OFF_CNT, 0, 64 * sizeof(unsigned), stream);
  WPREP<<<dim3(128), dim3(512), 0, stream>>>(
      W_se_pre, W_query, W_key, W_se, W_sap, W_av, W_f1, ws);
  FUSED3<<<dim3(256), dim3(512), 0, stream>>>(
      states, policies, actions, b_se_pre, b_se, b_sap, W_f2, ws, out);
}

// Round 13
// 75.201 us; speedup vs baseline: 1.4728x; 1.1044x over previous
//
#include <hip/hip_runtime.h>

#define DEVFN __device__ __forceinline__

constexpr int BNN = 64 * 64 * 64;              // 262144 per output tensor
constexpr float SCALE = 0.08838834764831845f;  // 1/sqrt(128)
constexpr float NSLOPE = 0.01f;

// ---- ws layout (floats) ---- (11.93 MB, proven)
constexpr int OFF_WPRET = 0;       // [64][128]
constexpr int OFF_WQT   = 8192;    // [128][128] (make_M input)
constexpr int OFF_M     = 24576;   // [128][128]  M = Wq^T Wk
constexpr int OFF_WSET  = 40960;   // [128][128]
constexpr int OFF_WSAPT = 57344;   // [96][128]
constexpr int OFF_WAVT  = 69632;   // [128][128]
constexpr int OFF_WF1T  = 86016;   // [128][64]
constexpr int OFF_E     = 98304;    // [4096][128] e row-major
constexpr int OFF_Q     = 622592;   // [4096][128] f then f2 (same-row aliasing, safe)
constexpr int OFF_ET    = 1146880;  // [B][128][64] e feature-major
constexpr int OFF_SET   = 1671168;  // [B][128][64] se feature-major
constexpr int OFF_HA    = 2195456;  // [B][64][64]
constexpr int OFF_HD    = 2719744;  // [B][64][64]

// ============ staging: global (tight) -> LDS (padded pitch) ============

template<int NT>
DEVFN void st128(int tid, const float* __restrict__ src, float* __restrict__ Bs, int rows) {
  const int n4 = rows * 32;
  for (int idx = tid; idx < n4; idx += NT) {
    const int r = idx >> 5, c = idx & 31;
    *reinterpret_cast<float4*>(&Bs[r * 132 + c * 4]) =
        *reinterpret_cast<const float4*>(&src[r * 128 + c * 4]);
  }
}

template<int NT>
DEVFN void st64r(int tid, const float* __restrict__ src, float* __restrict__ Bs, int rows) {
  const int n4 = rows * 16;
  for (int idx = tid; idx < n4; idx += NT) {
    const int r = idx >> 4, c = idx & 15;
    *reinterpret_cast<float4*>(&Bs[r * 68 + c * 4]) =
        *reinterpret_cast<const float4*>(&src[r * 64 + c * 4]);
  }
}

// Coalesced feature-major writeout (256 thr): src LDS [16][132] -> dst global [128][64]
DEVFN void wrT(int tid, const float* __restrict__ S, float* __restrict__ dst, int rq) {
#pragma unroll
  for (int h = 0; h < 2; ++h) {
    const int idx = tid + h * 256;
    const int fr = idx >> 2, a4 = idx & 3;
    float t[4];
#pragma unroll
    for (int i = 0; i < 4; ++i) t[i] = S[(a4 * 4 + i) * 132 + fr];
    float4 v; v.x = t[0]; v.y = t[1]; v.z = t[2]; v.w = t[3];
    *reinterpret_cast<float4*>(&dst[fr * 64 + rq * 16 + a4 * 4]) = v;
  }
}

// ============ RPT=2 GEMM cores: 256 thr, 16 rows x 128 cols, 2 rows x 4 cols/thread ===
// c0 = 4*(tid&31) spans the 128-col row within each wave half (2-way broadcast,
// conflict-free); one B float4 feeds 16 FLOP -> 2x the FLOP/LDS-byte of RPT=1.

DEVFN void g1(int tid, const float* __restrict__ A, int lda,
              const float* __restrict__ Bs, int K,
              float (&a0)[4], float (&a1)[4]) {
  const int c0 = (tid & 31) * 4, r0 = (tid >> 5) * 2;
  const float* __restrict__ A0 = A + r0 * lda;
  const float* __restrict__ A1 = A0 + lda;
#pragma unroll 8
  for (int k = 0; k < K; ++k) {
    const float4 bv = *reinterpret_cast<const float4*>(&Bs[k * 132 + c0]);
    const float x = A0[k], y = A1[k];
    a0[0] += x * bv.x; a0[1] += x * bv.y; a0[2] += x * bv.z; a0[3] += x * bv.w;
    a1[0] += y * bv.x; a1[1] += y * bv.y; a1[2] += y * bv.z; a1[3] += y * bv.w;
  }
}

DEVFN void g2A(int tid, const float* __restrict__ Ax, const float* __restrict__ Ay,
               int lda, const float* __restrict__ Bs, int K,
               float (&p0)[4], float (&p1)[4], float (&q0)[4], float (&q1)[4]) {
  const int c0 = (tid & 31) * 4, r0 = (tid >> 5) * 2;
  const float* __restrict__ X0 = Ax + r0 * lda;
  const float* __restrict__ X1 = X0 + lda;
  const float* __restrict__ Y0 = Ay + r0 * lda;
  const float* __restrict__ Y1 = Y0 + lda;
#pragma unroll 4
  for (int k = 0; k < K; ++k) {
    const float4 bv = *reinterpret_cast<const float4*>(&Bs[k * 132 + c0]);
    const float x0 = X0[k], x1 = X1[k], y0 = Y0[k], y1 = Y1[k];
    p0[0] += x0 * bv.x; p0[1] += x0 * bv.y; p0[2] += x0 * bv.z; p0[3] += x0 * bv.w;
    p1[0] += x1 * bv.x; p1[1] += x1 * bv.y; p1[2] += x1 * bv.z; p1[3] += x1 * bv.w;
    q0[0] += y0 * bv.x; q0[1] += y0 * bv.y; q0[2] += y0 * bv.z; q0[3] += y0 * bv.w;
    q1[0] += y1 * bv.x; q1[1] += y1 * bv.y; q1[2] += y1 * bv.z; q1[3] += y1 * bv.w;
  }
}

// 64-col variants: 2 rows x 2 cols, B pitch 68 float2
DEVFN void gH(int tid, const float* __restrict__ A, int lda,
              const float* __restrict__ Bs, int K,
              float (&a0)[2], float (&a1)[2]) {
  const int c0 = (tid & 31) * 2, r0 = (tid >> 5) * 2;
  const float* __restrict__ A0 = A + r0 * lda;
  const float* __restrict__ A1 = A0 + lda;
#pragma unroll 8
  for (int k = 0; k < K; ++k) {
    const float2 bv = *reinterpret_cast<const float2*>(&Bs[k * 68 + c0]);
    const float x = A0[k], y = A1[k];
    a0[0] += x * bv.x; a0[1] += x * bv.y;
    a1[0] += y * bv.x; a1[1] += y * bv.y;
  }
}

DEVFN void gH2(int tid, const float* __restrict__ Ax, const float* __restrict__ Ay,
               int lda, const float* __restrict__ Bs, int K,
               float (&p0)[2], float (&p1)[2], float (&q0)[2], float (&q1)[2]) {
  const int c0 = (tid & 31) * 2, r0 = (tid >> 5) * 2;
  const float* __restrict__ X0 = Ax + r0 * lda;
  const float* __restrict__ X1 = X0 + lda;
  const float* __restrict__ Y0 = Ay + r0 * lda;
  const float* __restrict__ Y1 = Y0 + lda;
#pragma unroll 4
  for (int k = 0; k < K; ++k) {
    const float2 bv = *reinterpret_cast<const float2*>(&Bs[k * 68 + c0]);
    const float x0 = X0[k], x1 = X1[k], y0 = Y0[k], y1 = Y1[k];
    p0[0] += x0 * bv.x; p0[1] += x0 * bv.y;
    p1[0] += x1 * bv.x; p1[1] += x1 * bv.y;
    q0[0] += y0 * bv.x; q0[1] += y0 * bv.y;
    q1[0] += y1 * bv.x; q1[1] += y1 * bv.y;
  }
}

template<bool ACT, bool HASB>
DEVFN void epi(int tid, const float (&a0)[4], const float (&a1)[4],
               float* __restrict__ O, int ldo, const float* __restrict__ bias) {
  const int c0 = (tid & 31) * 4, r0 = (tid >> 5) * 2;
  float t0[4], t1[4];
#pragma unroll
  for (int i = 0; i < 4; ++i) {
    float bv = 0.f;
    if constexpr (HASB) bv = bias[c0 + i];
    float x = a0[i] + bv, y = a1[i] + bv;
    if constexpr (ACT) { x = (x > 0.f) ? x : NSLOPE * x; y = (y > 0.f) ? y : NSLOPE * y; }
    t0[i] = x; t1[i] = y;
  }
  float4 v0; v0.x = t0[0]; v0.y = t0[1]; v0.z = t0[2]; v0.w = t0[3];
  float4 v1; v1.x = t1[0]; v1.y = t1[1]; v1.z = t1[2]; v1.w = t1[3];
  *reinterpret_cast<float4*>(&O[r0 * ldo + c0]) = v0;
  *reinterpret_cast<float4*>(&O[(r0 + 1) * ldo + c0]) = v1;
}

// ============ score + softmax: 256 thr, 16 rows (4 rows per wave) ============

DEVFN void score_half(int tid, const float* __restrict__ Qs, int hoff,
                      const float* __restrict__ Ks, float (&acc)[4]) {
  const int j = tid & 63, iw = tid >> 6;
#pragma unroll 2
  for (int kt = 0; kt < 64; kt += 8) {
    float qv[4][8];
#pragma unroll
    for (int r = 0; r < 4; ++r) {
      *reinterpret_cast<float4*>(&qv[r][0]) =
          *reinterpret_cast<const float4*>(&Qs[(iw * 4 + r) * 132 + hoff + kt]);
      *reinterpret_cast<float4*>(&qv[r][4]) =
          *reinterpret_cast<const float4*>(&Qs[(iw * 4 + r) * 132 + hoff + kt + 4]);
    }
#pragma unroll
    for (int kk = 0; kk < 8; ++kk) {
      const float kv = Ks[(kt + kk) * 68 + j];
#pragma unroll
      for (int r = 0; r < 4; ++r) acc[r] += qv[r][kk] * kv;
    }
  }
}

DEVFN void softmax_write(int tid, float (&acc)[4], float* __restrict__ Wp,
                         float* __restrict__ gout) {
  const int j = tid & 63, iw = tid >> 6;
#pragma unroll
  for (int r = 0; r < 4; ++r) {
    float v = acc[r] * SCALE;
    float m = v;
#pragma unroll
    for (int off = 32; off > 0; off >>= 1) m = fmaxf(m, __shfl_xor(m, off, 64));
    const float p = __expf(v - m);
    float s = p;
#pragma unroll
    for (int off = 32; off > 0; off >>= 1) s += __shfl_xor(s, off, 64);
    const float w = p / s;
    Wp[(iw * 4 + r) * 68 + j] = w;
    gout[(iw * 4 + r) * 64 + j] = w;
  }
}

// ===================== kernels =====================

__global__ void transpose_all(const float* __restrict__ Wpre, const float* __restrict__ Wq,
                              const float* __restrict__ Wse, const float* __restrict__ Wsap,
                              const float* __restrict__ Wav, const float* __restrict__ Wf1,
                              float* __restrict__ ws) {
  const int m = blockIdx.y;
  const float* src; int Cout, K, off;
  switch (m) {
    case 0: src = Wpre; Cout = 128; K = 64;  off = OFF_WPRET; break;
    case 1: src = Wq;   Cout = 128; K = 128; off = OFF_WQT;   break;
    case 2: src = Wse;  Cout = 128; K = 128; off = OFF_WSET;  break;
    case 3: src = Wsap; Cout = 128; K = 96;  off = OFF_WSAPT; break;
    case 4: src = Wav;  Cout = 128; K = 128; off = OFF_WAVT;  break;
    default: src = Wf1; Cout = 64;  K = 128; off = OFF_WF1T;  break;
  }
  const int idx = blockIdx.x * 256 + threadIdx.x;
  if (idx < Cout * K) {
    const int c = idx / K, k = idx - c * K;
    ws[off + k * Cout + c] = src[idx];
  }
}

// M = Wq^T @ Wk. Grid 8 x 512, 16 rows.
__global__ __launch_bounds__(512) void make_M(const float* __restrict__ Wkey,
                                              float* __restrict__ ws) {
  __shared__ float As[16 * 132];
  __shared__ float Bs[64 * 132];
  const int tid = threadIdx.x;
  const int r0 = blockIdx.x * 16;
  {
    const int r = tid >> 5, c = tid & 31;
    *reinterpret_cast<float4*>(&As[r * 132 + c * 4]) =
        *reinterpret_cast<const float4*>(&ws[OFF_WQT + (r0 + r) * 128 + c * 4]);
  }
  const int c0 = (tid & 31) * 4, rg = tid >> 5;
  float acc[4] = {};
  for (int h = 0; h < 2; ++h) {
    __syncthreads();
    st128<512>(tid, Wkey + h * 8192, Bs, 64);
    __syncthreads();
#pragma unroll 8
    for (int k = 0; k < 64; ++k) {
      const float4 bv = *reinterpret_cast<const float4*>(&Bs[k * 132 + c0]);
      const float a = As[rg * 132 + h * 64 + k];
      acc[0] += a * bv.x; acc[1] += a * bv.y; acc[2] += a * bv.z; acc[3] += a * bv.w;
    }
  }
  float4 v; v.x = acc[0]; v.y = acc[1]; v.z = acc[2]; v.w = acc[3];
  *reinterpret_cast<float4*>(&ws[OFF_M + (r0 + rg) * 128 + c0]) = v;
}

// P1: grid 256 (XCD-swizzled), 256 thr, 16 rows, RPT=2 cores.
__global__ __launch_bounds__(256) void P1(const float* __restrict__ states,
                                          const float* __restrict__ policies,
                                          const float* __restrict__ actions,
                                          const float* __restrict__ b_sap,
                                          const float* __restrict__ b_se_pre,
                                          float* __restrict__ ws) {
  __shared__ float S[16 * 68];
  __shared__ float Aa[16 * 36], Ap[16 * 36];
  __shared__ float Ea[16 * 132];   // E_act -> AVs
  __shared__ float Ep[16 * 132], Dd[16 * 132], Er[16 * 132];
  __shared__ float Bs[64 * 132];
  const int tid = threadIdx.x;
  const int wid = ((blockIdx.x & 7) << 5) | (blockIdx.x >> 3);
  const int b = wid >> 2, rq = wid & 3;
  const int r0g = b * 64 + rq * 16;

  for (int idx = tid; idx < 1024; idx += 256) {
    const int r = idx >> 6, c = idx & 63;
    S[r * 68 + c] = states[(r0g + r) * 64 + c];
  }
  for (int idx = tid; idx < 512; idx += 256) {
    const int r = idx >> 5, c = idx & 31;
    Aa[r * 36 + c] = actions[(r0g + r) * 32 + c];
    Ap[r * 36 + c] = policies[(r0g + r) * 32 + c];
  }
  st128<256>(tid, ws + OFF_WSAPT, Bs, 64);
  __syncthreads();
  // common (state) part of Esap, K=64
  float cm0[4] = {}, cm1[4] = {};
  g1(tid, S, 68, Bs, 64, cm0, cm1);
  __syncthreads();
  st128<256>(tid, ws + OFF_WSAPT + 8192, Bs, 32);
  __syncthreads();
  // act/pol tails, K=32
  float aa0[4] = {cm0[0], cm0[1], cm0[2], cm0[3]};
  float aa1[4] = {cm1[0], cm1[1], cm1[2], cm1[3]};
  float ap0[4] = {cm0[0], cm0[1], cm0[2], cm0[3]};
  float ap1[4] = {cm1[0], cm1[1], cm1[2], cm1[3]};
  g2A(tid, Aa, Ap, 36, Bs, 32, aa0, aa1, ap0, ap1);
  epi<true, true>(tid, aa0, aa1, Ea, 132, b_sap);
  epi<true, true>(tid, ap0, ap1, Ep, 132, b_sap);
  __syncthreads();
  for (int idx = tid; idx < 2048; idx += 256) {
    const int r = idx >> 7, c = idx & 127;
    Ep[r * 132 + c] -= Ea[r * 132 + c];
  }
  __syncthreads();
  // av_act / delta (K=128 in 2 chunks)
  st128<256>(tid, ws + OFF_WAVT, Bs, 64);
  __syncthreads();
  float av0[4] = {}, av1[4] = {}, dl0[4] = {}, dl1[4] = {};
  g2A(tid, Ea, Ep, 132, Bs, 64, av0, av1, dl0, dl1);
  __syncthreads();
  st128<256>(tid, ws + OFF_WAVT + 8192, Bs, 64);
  __syncthreads();
  g2A(tid, Ea + 64, Ep + 64, 132, Bs, 64, av0, av1, dl0, dl1);
  __syncthreads();  // all reads of Ea done before overwrite
  epi<false, false>(tid, av0, av1, Ea, 132, nullptr);  // Ea := AVs
  epi<false, false>(tid, dl0, dl1, Dd, 132, nullptr);
  __syncthreads();
  // hd = delta @ Wf1^T ; ha = av_act @ Wf1^T (shared staging, K=128)
  st64r<256>(tid, ws + OFF_WF1T, Bs, 64);
  __syncthreads();
  float h0[2] = {}, h1[2] = {}, ha0[2] = {}, ha1[2] = {};
  gH2(tid, Dd, Ea, 132, Bs, 64, h0, h1, ha0, ha1);
  __syncthreads();
  st64r<256>(tid, ws + OFF_WF1T + 4096, Bs, 64);
  __syncthreads();
  gH2(tid, Dd + 64, Ea + 64, 132, Bs, 64, h0, h1, ha0, ha1);
  {
    const int c0 = (tid & 31) * 2, r0 = (tid >> 5) * 2;
    float2 v0h; v0h.x = h0[0]; v0h.y = h0[1];
    float2 v1h; v1h.x = h1[0]; v1h.y = h1[1];
    float2 v0a; v0a.x = ha0[0]; v0a.y = ha0[1];
    float2 v1a; v1a.x = ha1[0]; v1a.y = ha1[1];
    *reinterpret_cast<float2*>(&ws[OFF_HD + (r0g + r0) * 64 + c0]) = v0h;
    *reinterpret_cast<float2*>(&ws[OFF_HD + (r0g + r0 + 1) * 64 + c0]) = v1h;
    *reinterpret_cast<float2*>(&ws[OFF_HA + (r0g + r0) * 64 + c0]) = v0a;
    *reinterpret_cast<float2*>(&ws[OFF_HA + (r0g + r0 + 1) * 64 + c0]) = v1a;
  }
  __syncthreads();
  // e = lrelu(states @ Wpre^T + b) -> Er + ws.E
  st128<256>(tid, ws + OFF_WPRET, Bs, 64);
  __syncthreads();
  {
    float ae0[4] = {}, ae1[4] = {};
    g1(tid, S, 68, Bs, 64, ae0, ae1);
    const int c0 = (tid & 31) * 4, r0 = (tid >> 5) * 2;
    float t0[4], t1[4];
#pragma unroll
    for (int i = 0; i < 4; ++i) {
      const float bv = b_se_pre[c0 + i];
      float x = ae0[i] + bv, y = ae1[i] + bv;
      t0[i] = (x > 0.f) ? x : NSLOPE * x;
      t1[i] = (y > 0.f) ? y : NSLOPE * y;
    }
    float4 v0; v0.x = t0[0]; v0.y = t0[1]; v0.z = t0[2]; v0.w = t0[3];
    float4 v1; v1.x = t1[0]; v1.y = t1[1]; v1.z = t1[2]; v1.w = t1[3];
    *reinterpret_cast<float4*>(&Er[r0 * 132 + c0]) = v0;
    *reinterpret_cast<float4*>(&Er[(r0 + 1) * 132 + c0]) = v1;
    *reinterpret_cast<float4*>(&ws[OFF_E + (r0g + r0) * 128 + c0]) = v0;
    *reinterpret_cast<float4*>(&ws[OFF_E + (r0g + r0 + 1) * 128 + c0]) = v1;
  }
  __syncthreads();
  wrT(tid, Er, ws + OFF_ET + b * 8192, rq);
  st128<256>(tid, ws + OFF_M, Bs, 64);
  __syncthreads();
  // f = e @ M (K=128) -> ws.Q
  float af0[4] = {}, af1[4] = {};
  g1(tid, Er, 132, Bs, 64, af0, af1);
  __syncthreads();
  st128<256>(tid, ws + OFF_M + 8192, Bs, 64);
  __syncthreads();
  g1(tid, Er + 64, 132, Bs, 64, af0, af1);
  epi<false, false>(tid, af0, af1, ws + OFF_Q + r0g * 128, 128, nullptr);
}

// P3: grid 256 (swizzled), 256 thr, 16 rows. score1 -> w_pre ; av_pre ; se ; f2.
__global__ __launch_bounds__(256) void P3(const float* __restrict__ b_se,
                                          float* __restrict__ ws,
                                          float* __restrict__ out) {
  __shared__ float Qs[16 * 132];
  __shared__ float Bs[64 * 132];
  __shared__ float Wp[16 * 68], AV[16 * 132], SEr[16 * 132];
  const int tid = threadIdx.x;
  const int wid = ((blockIdx.x & 7) << 5) | (blockIdx.x >> 3);
  const int b = wid >> 2, rq = wid & 3;
  const int r0g = b * 64 + rq * 16;

  for (int idx = tid; idx < 512; idx += 256) {
    const int r = idx >> 5, c = idx & 31;
    *reinterpret_cast<float4*>(&Qs[r * 132 + c * 4]) =
        *reinterpret_cast<const float4*>(&ws[OFF_Q + (r0g + r) * 128 + c * 4]);
  }
  st64r<256>(tid, ws + OFF_ET + b * 8192, Bs, 64);
  __syncthreads();
  float sc[4] = {};
  score_half(tid, Qs, 0, Bs, sc);
  __syncthreads();
  st64r<256>(tid, ws + OFF_ET + b * 8192 + 4096, Bs, 64);
  __syncthreads();
  score_half(tid, Qs, 64, Bs, sc);
  softmax_write(tid, sc, Wp, out + BNN + b * 4096 + rq * 1024);
  __syncthreads();
  // av_pre = w_pre @ e[b] (K=64)
  st128<256>(tid, ws + OFF_E + b * 8192, Bs, 64);
  __syncthreads();
  {
    float a0[4] = {}, a1[4] = {};
    g1(tid, Wp, 68, Bs, 64, a0, a1);
    epi<false, false>(tid, a0, a1, AV, 132, nullptr);
  }
  __syncthreads();
  // se = lrelu(av_pre @ Wse^T + b_se) (K=128)
  st128<256>(tid, ws + OFF_WSET, Bs, 64);
  __syncthreads();
  float as0[4] = {}, as1[4] = {};
  g1(tid, AV, 132, Bs, 64, as0, as1);
  __syncthreads();
  st128<256>(tid, ws + OFF_WSET + 8192, Bs, 64);
  __syncthreads();
  g1(tid, AV + 64, 132, Bs, 64, as0, as1);
  {
    const int c0 = (tid & 31) * 4, r0 = (tid >> 5) * 2;
    float t0[4], t1[4];
#pragma unroll
    for (int i = 0; i < 4; ++i) {
      const float bv = b_se[c0 + i];
      float x = as0[i] + bv, y = as1[i] + bv;
      t0[i] = (x > 0.f) ? x : NSLOPE * x;
      t1[i] = (y > 0.f) ? y : NSLOPE * y;
    }
    float4 v0; v0.x = t0[0]; v0.y = t0[1]; v0.z = t0[2]; v0.w = t0[3];
    float4 v1; v1.x = t1[0]; v1.y = t1[1]; v1.z = t1[2]; v1.w = t1[3];
    *reinterpret_cast<float4*>(&SEr[r0 * 132 + c0]) = v0;
    *reinterpret_cast<float4*>(&SEr[(r0 + 1) * 132 + c0]) = v1;
  }
  __syncthreads();
  wrT(tid, SEr, ws + OFF_SET + b * 8192, rq);
  st128<256>(tid, ws + OFF_M, Bs, 64);
  __syncthreads();
  // f2 = se @ M (K=128) -> ws.Q
  float af0[4] = {}, af1[4] = {};
  g1(tid, SEr, 132, Bs, 64, af0, af1);
  __syncthreads();
  st128<256>(tid, ws + OFF_M + 8192, Bs, 64);
  __syncthreads();
  g1(tid, SEr + 64, 132, Bs, 64, af0, af1);
  epi<false, false>(tid, af0, af1, ws + OFF_Q + r0g * 128, 128, nullptr);
}

// P4: grid 256 (swizzled), 256 thr, 16 rows. score2 -> w ; h_base = w @ ha ; head.
__global__ __launch_bounds__(256) void P4(const float* __restrict__ Wf2g,
                                          float* __restrict__ ws,
                                          float* __restrict__ out) {
  __shared__ float Qs[16 * 132];
  __shared__ float Bs[64 * 132];
  __shared__ float Wp[16 * 68], Hb[16 * 66];
  __shared__ float Hd[64 * 69];
  __shared__ float Wf2s[64];
  const int tid = threadIdx.x;
  const int wid = ((blockIdx.x & 7) << 5) | (blockIdx.x >> 3);
  const int b = wid >> 2, rq = wid & 3;
  const int r0g = b * 64 + rq * 16;

  for (int idx = tid; idx < 4096; idx += 256)
    Hd[(idx >> 6) * 69 + (idx & 63)] = ws[OFF_HD + b * 4096 + idx];
  if (tid < 64) Wf2s[tid] = Wf2g[tid];
  for (int idx = tid; idx < 512; idx += 256) {
    const int r = idx >> 5, c = idx & 31;
    *reinterpret_cast<float4*>(&Qs[r * 132 + c * 4]) =
        *reinterpret_cast<const float4*>(&ws[OFF_Q + (r0g + r) * 128 + c * 4]);
  }
  st64r<256>(tid, ws + OFF_SET + b * 8192, Bs, 64);
  __syncthreads();
  float sc[4] = {};
  score_half(tid, Qs, 0, Bs, sc);
  __syncthreads();
  st64r<256>(tid, ws + OFF_SET + b * 8192 + 4096, Bs, 64);
  __syncthreads();
  score_half(tid, Qs, 64, Bs, sc);
  softmax_write(tid, sc, Wp, out + 2 * BNN + b * 4096 + rq * 1024);
  __syncthreads();
  // h_base = w @ ha[b] (K=64)
  st64r<256>(tid, ws + OFF_HA + b * 4096, Bs, 64);
  __syncthreads();
  float h0[2] = {}, h1[2] = {};
  gH(tid, Wp, 68, Bs, 64, h0, h1);
  {
    const int c0 = (tid & 31) * 2, r0 = (tid >> 5) * 2;
    float2 v0; v0.x = h0[0]; v0.y = h0[1];
    float2 v1; v1.x = h1[0]; v1.y = h1[1];
    *reinterpret_cast<float2*>(&Hb[r0 * 66 + c0]) = v0;
    *reinterpret_cast<float2*>(&Hb[(r0 + 1) * 66 + c0]) = v1;
  }
  __syncthreads();
  // head: value[i][j] = sum_f lrelu(Hb[i,f] + w[i,j]*Hd[j,f]) * Wf2[f]
  const int j = tid & 63, iw = tid >> 6;
  float wv[4], a4[4] = {0.f, 0.f, 0.f, 0.f};
#pragma unroll
  for (int r = 0; r < 4; ++r) wv[r] = Wp[(iw * 4 + r) * 68 + j];
  for (int f = 0; f < 64; ++f) {
    const float hdv = Hd[j * 69 + f];
    const float wf = Wf2s[f];
#pragma unroll
    for (int r = 0; r < 4; ++r) {
      float t = Hb[(iw * 4 + r) * 66 + f] + wv[r] * hdv;
      t = (t > 0.f) ? t : NSLOPE * t;
      a4[r] += t * wf;
    }
  }
#pragma unroll
  for (int r = 0; r < 4; ++r)
    out[(r0g + iw * 4 + r) * 64 + j] = a4[r];
}

extern "C" void kernel_launch(void* const* d_in, const int* in_sizes, int n_in,
                              void* d_out, int out_size, void* d_ws, size_t ws_size,
                              hipStream_t stream) {
  const float* states   = (const float*)d_in[0];
  const float* policies = (const float*)d_in[1];
  const float* actions  = (const float*)d_in[2];
  const float* W_se_pre = (const float*)d_in[3];
  const float* b_se_pre = (const float*)d_in[4];
  const float* W_key    = (const float*)d_in[5];
  const float* W_query  = (const float*)d_in[6];
  const float* W_se     = (const float*)d_in[7];
  const float* b_se     = (const float*)d_in[8];
  const float* W_sap    = (const float*)d_in[9];
  const float* b_sap    = (const float*)d_in[10];
  const float* W_av     = (const float*)d_in[11];
  const float* W_f1     = (const float*)d_in[12];
  const float* W_f2     = (const float*)d_in[13];
  float* out = (float*)d_out;
  float* ws  = (float*)d_ws;

  transpose_all<<<dim3(64, 6), dim3(256), 0, stream>>>(
      W_se_pre, W_query, W_se, W_sap, W_av, W_f1, ws);
  make_M<<<dim3(8), dim3(512), 0, stream>>>(W_key, ws);
  P1<<<dim3(256), dim3(256), 0, stream>>>(states, policies, actions, b_sap, b_se_pre, ws);
  P3<<<dim3(256), dim3(256), 0, stream>>>(b_se, ws, out);
  P4<<<dim3(256), dim3(256), 0, stream>>>(W_f2, ws, out);
}

// Round 15
// 62.113 us; speedup vs baseline: 1.7832x; 1.2107x over previous
//
#include <hip/hip_runtime.h>

#define DEVFN __device__ __forceinline__

constexpr int BNN = 64 * 64 * 64;              // 262144 per output tensor
constexpr float SCALE = 0.08838834764831845f;  // 1/sqrt(128)
constexpr float NSLOPE = 0.01f;

// ---- ws layout (floats) ---- (11.93 MB, proven)
constexpr int OFF_WPRET = 0;       // [64][128]
constexpr int OFF_M     = 24576;   // [128][128]  M = Wq^T Wk
constexpr int OFF_WSET  = 40960;   // [128][128]
constexpr int OFF_WSAPT = 57344;   // [96][128]
constexpr int OFF_WAVT  = 69632;   // [128][128]
constexpr int OFF_WF1T  = 86016;   // [128][64]
constexpr int OFF_E     = 98304;    // [4096][128] e row-major
constexpr int OFF_Q     = 622592;   // [4096][128] f then f2 (same-row aliasing, safe)
constexpr int OFF_ET    = 1146880;  // [B][128][64] e feature-major
constexpr int OFF_SET   = 1671168;  // [B][128][64] se feature-major
constexpr int OFF_HA    = 2195456;  // [B][64][64]
constexpr int OFF_HD    = 2719744;  // [B][64][64]

// ============ small helpers (functions, not macros — R14 died to macro capture) ============

DEVFN void fma4(float (&acc)[4], float a, const float4& bv) {
  acc[0] += a * bv.x; acc[1] += a * bv.y; acc[2] += a * bv.z; acc[3] += a * bv.w;
}
DEVFN void fma2(float (&acc)[2], float a, const float2& bv) {
  acc[0] += a * bv.x; acc[1] += a * bv.y;
}

// ============ staging: global (tight) -> LDS (padded pitch) ============

template<int NT>
DEVFN void st128(int tid, const float* __restrict__ src, float* __restrict__ Bs, int rows) {
  const int n4 = rows * 32;
  for (int idx = tid; idx < n4; idx += NT) {
    const int r = idx >> 5, c = idx & 31;
    *reinterpret_cast<float4*>(&Bs[r * 132 + c * 4]) =
        *reinterpret_cast<const float4*>(&src[r * 128 + c * 4]);
  }
}

template<int NT>
DEVFN void st64r(int tid, const float* __restrict__ src, float* __restrict__ Bs, int rows) {
  const int n4 = rows * 16;
  for (int idx = tid; idx < n4; idx += NT) {
    const int r = idx >> 4, c = idx & 15;
    *reinterpret_cast<float4*>(&Bs[r * 68 + c * 4]) =
        *reinterpret_cast<const float4*>(&src[r * 64 + c * 4]);
  }
}

// Coalesced feature-major writeout (512 thr): src LDS [16][132] -> dst global [128][64]
DEVFN void wrT(int tid, const float* __restrict__ S, float* __restrict__ dst, int rq) {
  const int fr = tid >> 2, a4 = tid & 3;
  float t[4];
#pragma unroll
  for (int i = 0; i < 4; ++i) t[i] = S[(a4 * 4 + i) * 132 + fr];
  float4 v; v.x = t[0]; v.y = t[1]; v.z = t[2]; v.w = t[3];
  *reinterpret_cast<float4*>(&dst[fr * 64 + rq * 16 + a4 * 4]) = v;
}

// ============ GEMM cores: 512 thr, 16 rows x 128 cols, 1 row x 4 cols/thread ============
// A loaded as float4 per 4 k's (rows are 16B-aligned: all pitches divisible by 4).

DEVFN void g1(int tid, const float* __restrict__ A, int lda,
              const float* __restrict__ Bs, int K, float (&acc)[4]) {
  const int c0 = (tid & 31) * 4, rg = tid >> 5;
  const float* __restrict__ Ar = A + rg * lda;
#pragma unroll 4
  for (int k4 = 0; k4 < K; k4 += 4) {
    const float4 a4 = *reinterpret_cast<const float4*>(&Ar[k4]);
    const float4 b0 = *reinterpret_cast<const float4*>(&Bs[(k4 + 0) * 132 + c0]);
    const float4 b1 = *reinterpret_cast<const float4*>(&Bs[(k4 + 1) * 132 + c0]);
    const float4 b2 = *reinterpret_cast<const float4*>(&Bs[(k4 + 2) * 132 + c0]);
    const float4 b3 = *reinterpret_cast<const float4*>(&Bs[(k4 + 3) * 132 + c0]);
    fma4(acc, a4.x, b0); fma4(acc, a4.y, b1); fma4(acc, a4.z, b2); fma4(acc, a4.w, b3);
  }
}

DEVFN void g2A(int tid, const float* __restrict__ A0, const float* __restrict__ A1,
               int lda, const float* __restrict__ Bs, int K,
               float (&a0)[4], float (&a1)[4]) {
  const int c0 = (tid & 31) * 4, rg = tid >> 5;
  const float* __restrict__ X = A0 + rg * lda;
  const float* __restrict__ Y = A1 + rg * lda;
#pragma unroll 2
  for (int k4 = 0; k4 < K; k4 += 4) {
    const float4 x4 = *reinterpret_cast<const float4*>(&X[k4]);
    const float4 y4 = *reinterpret_cast<const float4*>(&Y[k4]);
    const float4 b0 = *reinterpret_cast<const float4*>(&Bs[(k4 + 0) * 132 + c0]);
    const float4 b1 = *reinterpret_cast<const float4*>(&Bs[(k4 + 1) * 132 + c0]);
    const float4 b2 = *reinterpret_cast<const float4*>(&Bs[(k4 + 2) * 132 + c0]);
    const float4 b3 = *reinterpret_cast<const float4*>(&Bs[(k4 + 3) * 132 + c0]);
    fma4(a0, x4.x, b0); fma4(a1, y4.x, b0);
    fma4(a0, x4.y, b1); fma4(a1, y4.y, b1);
    fma4(a0, x4.z, b2); fma4(a1, y4.z, b2);
    fma4(a0, x4.w, b3); fma4(a1, y4.w, b3);
  }
}

// 64-col variants: 1 row x 2 cols, B pitch 68 float2
DEVFN void gH(int tid, const float* __restrict__ A, int lda,
              const float* __restrict__ Bs, int K, float (&acc)[2]) {
  const int c0 = (tid & 31) * 2, rg = tid >> 5;
  const float* __restrict__ Ar = A + rg * lda;
#pragma unroll 4
  for (int k4 = 0; k4 < K; k4 += 4) {
    const float4 a4 = *reinterpret_cast<const float4*>(&Ar[k4]);
    const float2 b0 = *reinterpret_cast<const float2*>(&Bs[(k4 + 0) * 68 + c0]);
    const float2 b1 = *reinterpret_cast<const float2*>(&Bs[(k4 + 1) * 68 + c0]);
    const float2 b2 = *reinterpret_cast<const float2*>(&Bs[(k4 + 2) * 68 + c0]);
    const float2 b3 = *reinterpret_cast<const float2*>(&Bs[(k4 + 3) * 68 + c0]);
    fma2(acc, a4.x, b0); fma2(acc, a4.y, b1); fma2(acc, a4.z, b2); fma2(acc, a4.w, b3);
  }
}

DEVFN void gH2(int tid, const float* __restrict__ A0, const float* __restrict__ A1,
               int lda, const float* __restrict__ Bs, int K,
               float (&a0)[2], float (&a1)[2]) {
  const int c0 = (tid & 31) * 2, rg = tid >> 5;
  const float* __restrict__ X = A0 + rg * lda;
  const float* __restrict__ Y = A1 + rg * lda;
#pragma unroll 2
  for (int k4 = 0; k4 < K; k4 += 4) {
    const float4 x4 = *reinterpret_cast<const float4*>(&X[k4]);
    const float4 y4 = *reinterpret_cast<const float4*>(&Y[k4]);
    const float2 b0 = *reinterpret_cast<const float2*>(&Bs[(k4 + 0) * 68 + c0]);
    const float2 b1 = *reinterpret_cast<const float2*>(&Bs[(k4 + 1) * 68 + c0]);
    const float2 b2 = *reinterpret_cast<const float2*>(&Bs[(k4 + 2) * 68 + c0]);
    const float2 b3 = *reinterpret_cast<const float2*>(&Bs[(k4 + 3) * 68 + c0]);
    fma2(a0, x4.x, b0); fma2(a1, y4.x, b0);
    fma2(a0, x4.y, b1); fma2(a1, y4.y, b1);
    fma2(a0, x4.z, b2); fma2(a1, y4.z, b2);
    fma2(a0, x4.w, b3); fma2(a1, y4.w, b3);
  }
}

template<bool ACT, bool HASB>
DEVFN void epi(int tid, const float (&acc)[4], float* __restrict__ O, int ldo,
               const float* __restrict__ bias) {
  const int c0 = (tid & 31) * 4, rg = tid >> 5;
  float t[4];
#pragma unroll
  for (int i = 0; i < 4; ++i) {
    float x = acc[i];
    if constexpr (HASB) x += bias[c0 + i];
    if constexpr (ACT) x = (x > 0.f) ? x : NSLOPE * x;
    t[i] = x;
  }
  float4 v; v.x = t[0]; v.y = t[1]; v.z = t[2]; v.w = t[3];
  *reinterpret_cast<float4*>(&O[rg * ldo + c0]) = v;
}

// ============ score (K=128 in one pass) + softmax: 512 thr, 16 rows ============

DEVFN void score_full(int tid, const float* __restrict__ Qs,
                      const float* __restrict__ Ks, float (&acc)[2]) {
  const int j = tid & 63, iw = tid >> 6;
#pragma unroll 2
  for (int kt = 0; kt < 128; kt += 8) {
    float qv[2][8];
#pragma unroll
    for (int r = 0; r < 2; ++r) {
      *reinterpret_cast<float4*>(&qv[r][0]) =
          *reinterpret_cast<const float4*>(&Qs[(iw * 2 + r) * 132 + kt]);
      *reinterpret_cast<float4*>(&qv[r][4]) =
          *reinterpret_cast<const float4*>(&Qs[(iw * 2 + r) * 132 + kt + 4]);
    }
#pragma unroll
    for (int kk = 0; kk < 8; ++kk) {
      const float kv = Ks[(kt + kk) * 68 + j];
      acc[0] += qv[0][kk] * kv;
      acc[1] += qv[1][kk] * kv;
    }
  }
}

DEVFN void softmax_write(int tid, float (&acc)[2], float* __restrict__ Wp,
                         float* __restrict__ gout) {
  const int j = tid & 63, iw = tid >> 6;
#pragma unroll
  for (int r = 0; r < 2; ++r) {
    float v = acc[r] * SCALE;
    float m = v;
#pragma unroll
    for (int off = 32; off > 0; off >>= 1) m = fmaxf(m, __shfl_xor(m, off, 64));
    const float p = __expf(v - m);
    float s = p;
#pragma unroll
    for (int off = 32; off > 0; off >>= 1) s += __shfl_xor(s, off, 64);
    const float w = p / s;
    Wp[(iw * 2 + r) * 68 + j] = w;
    gout[(iw * 2 + r) * 64 + j] = w;
  }
}

// ===================== kernel 1: weight transposes + M = Wq^T Wk =====================

__global__ __launch_bounds__(512) void WPREP(const float* __restrict__ Wpre,
                                             const float* __restrict__ Wq,
                                             const float* __restrict__ Wkey,
                                             const float* __restrict__ Wse,
                                             const float* __restrict__ Wsap,
                                             const float* __restrict__ Wav,
                                             const float* __restrict__ Wf1,
                                             float* __restrict__ ws) {
  __shared__ float As[16 * 132];
  __shared__ float Bs[64 * 132];
  const int tid = threadIdx.x, bid = blockIdx.x;
  if (bid < 120) {
    const int gt = bid * 512 + tid;
    if (gt < 8192) {                       // Wpre [128][64] -> WPRET [64][128]
      const int c = gt >> 6, k = gt & 63;
      ws[OFF_WPRET + k * 128 + c] = Wpre[gt];
    } else if (gt < 24576) {               // Wse -> WSET
      const int i = gt - 8192, c = i >> 7, k = i & 127;
      ws[OFF_WSET + k * 128 + c] = Wse[i];
    } else if (gt < 36864) {               // Wsap [128][96] -> WSAPT [96][128]
      const int i = gt - 24576, c = i / 96, k = i - c * 96;
      ws[OFF_WSAPT + k * 128 + c] = Wsap[i];
    } else if (gt < 53248) {               // Wav -> WAVT
      const int i = gt - 36864, c = i >> 7, k = i & 127;
      ws[OFF_WAVT + k * 128 + c] = Wav[i];
    } else if (gt < 61440) {               // Wf1 [64][128] -> WF1T [128][64]
      const int i = gt - 53248, c = i >> 7, k = i & 127;
      ws[OFF_WF1T + k * 64 + c] = Wf1[i];
    }
  } else {
    const int r0 = (bid - 120) * 16;
    for (int idx = tid; idx < 2048; idx += 512) {
      const int r = idx & 15, o = idx >> 4;
      As[r * 132 + o] = Wq[o * 128 + r0 + r];
    }
    const int c0 = (tid & 31) * 4, rg = tid >> 5;
    float acc[4] = {};
    for (int h = 0; h < 2; ++h) {
      __syncthreads();
      st128<512>(tid, Wkey + h * 8192, Bs, 64);
      __syncthreads();
#pragma unroll 8
      for (int k = 0; k < 64; ++k) {
        const float4 bv = *reinterpret_cast<const float4*>(&Bs[k * 132 + c0]);
        fma4(acc, As[rg * 132 + h * 64 + k], bv);
      }
    }
    float4 v; v.x = acc[0]; v.y = acc[1]; v.z = acc[2]; v.w = acc[3];
    *reinterpret_cast<float4*>(&ws[OFF_M + (r0 + rg) * 128 + c0]) = v;
  }
}

// P1: grid 256 (XCD-swizzled), 512 thr, 16 rows.
__global__ __launch_bounds__(512) void P1(const float* __restrict__ states,
                                          const float* __restrict__ policies,
                                          const float* __restrict__ actions,
                                          const float* __restrict__ b_sap,
                                          const float* __restrict__ b_se_pre,
                                          float* __restrict__ ws) {
  __shared__ float S[16 * 68];
  __shared__ float Aa[16 * 36], Ap[16 * 36];
  __shared__ float Ea[16 * 132];   // E_act -> AVs
  __shared__ float Ep[16 * 132], Dd[16 * 132], Er[16 * 132];
  __shared__ float Bs[8704];
  const int tid = threadIdx.x;
  const int wid = ((blockIdx.x & 7) << 5) | (blockIdx.x >> 3);
  const int b = wid >> 2, rq = wid & 3;
  const int r0g = b * 64 + rq * 16;

  for (int idx = tid; idx < 1024; idx += 512) {
    const int r = idx >> 6, c = idx & 63;
    S[r * 68 + c] = states[(r0g + r) * 64 + c];
  }
  {
    const int r = tid >> 5, c = tid & 31;
    Aa[r * 36 + c] = actions[(r0g + r) * 32 + c];
    Ap[r * 36 + c] = policies[(r0g + r) * 32 + c];
  }
  st128<512>(tid, ws + OFF_WSAPT, Bs, 64);
  __syncthreads();
  // common (state) part of Esap, K=64
  float cm[4] = {};
  g1(tid, S, 68, Bs, 64, cm);
  __syncthreads();
  st128<512>(tid, ws + OFF_WSAPT + 8192, Bs, 32);
  __syncthreads();
  // act/pol tails, K=32
  float aa[4] = {cm[0], cm[1], cm[2], cm[3]};
  float ap[4] = {cm[0], cm[1], cm[2], cm[3]};
  g2A(tid, Aa, Ap, 36, Bs, 32, aa, ap);
  epi<true, true>(tid, aa, Ea, 132, b_sap);
  epi<true, true>(tid, ap, Ep, 132, b_sap);
  __syncthreads();
  for (int idx = tid; idx < 2048; idx += 512) {
    const int r = idx >> 7, c = idx & 127;
    Ep[r * 132 + c] -= Ea[r * 132 + c];
  }
  __syncthreads();
  // av_act / delta (K=128 in 2 chunks)
  st128<512>(tid, ws + OFF_WAVT, Bs, 64);
  __syncthreads();
  float av[4] = {}, dl[4] = {};
  g2A(tid, Ea, Ep, 132, Bs, 64, av, dl);
  __syncthreads();
  st128<512>(tid, ws + OFF_WAVT + 8192, Bs, 64);
  __syncthreads();
  g2A(tid, Ea + 64, Ep + 64, 132, Bs, 64, av, dl);
  __syncthreads();  // all reads of Ea done before overwrite
  epi<false, false>(tid, av, Ea, 132, nullptr);  // Ea := AVs
  epi<false, false>(tid, dl, Dd, 132, nullptr);
  __syncthreads();
  // hd = delta @ Wf1^T ; ha = av_act @ Wf1^T (shared staging, [128][68] in one pass)
  st64r<512>(tid, ws + OFF_WF1T, Bs, 128);
  __syncthreads();
  float ah[2] = {}, aha[2] = {};
  gH2(tid, Dd, Ea, 132, Bs, 64, ah, aha);
  gH2(tid, Dd + 64, Ea + 64, 132, Bs + 64 * 68, 64, ah, aha);
  {
    const int c0 = (tid & 31) * 2, rg = tid >> 5;
    float2 vh; vh.x = ah[0]; vh.y = ah[1];
    float2 va; va.x = aha[0]; va.y = aha[1];
    *reinterpret_cast<float2*>(&ws[OFF_HD + (r0g + rg) * 64 + c0]) = vh;
    *reinterpret_cast<float2*>(&ws[OFF_HA + (r0g + rg) * 64 + c0]) = va;
  }
  __syncthreads();
  // e = lrelu(states @ Wpre^T + b) -> Er + ws.E
  st128<512>(tid, ws + OFF_WPRET, Bs, 64);
  __syncthreads();
  {
    float ae[4] = {};
    g1(tid, S, 68, Bs, 64, ae);
    const int c0 = (tid & 31) * 4, rg = tid >> 5;
    float t[4];
#pragma unroll
    for (int i = 0; i < 4; ++i) {
      float x = ae[i] + b_se_pre[c0 + i];
      t[i] = (x > 0.f) ? x : NSLOPE * x;
    }
    float4 v; v.x = t[0]; v.y = t[1]; v.z = t[2]; v.w = t[3];
    *reinterpret_cast<float4*>(&Er[rg * 132 + c0]) = v;
    *reinterpret_cast<float4*>(&ws[OFF_E + (r0g + rg) * 128 + c0]) = v;
  }
  __syncthreads();
  wrT(tid, Er, ws + OFF_ET + b * 8192, rq);
  st128<512>(tid, ws + OFF_M, Bs, 64);
  __syncthreads();
  // f = e @ M (K=128) -> ws.Q
  float af[4] = {};
  g1(tid, Er, 132, Bs, 64, af);
  __syncthreads();
  st128<512>(tid, ws + OFF_M + 8192, Bs, 64);
  __syncthreads();
  g1(tid, Er + 64, 132, Bs, 64, af);
  epi<false, false>(tid, af, ws + OFF_Q + r0g * 128, 128, nullptr);
}

// P3: grid 256 (swizzled), 512 thr, 16 rows. score1 -> w_pre ; av_pre ; se ; f2.
__global__ __launch_bounds__(512) void P3(const float* __restrict__ b_se,
                                          float* __restrict__ ws,
                                          float* __restrict__ out) {
  __shared__ float Qs[16 * 132];
  __shared__ float Bs[8704];
  __shared__ float Wp[16 * 68], AV[16 * 132], SEr[16 * 132];
  const int tid = threadIdx.x;
  const int wid = ((blockIdx.x & 7) << 5) | (blockIdx.x >> 3);
  const int b = wid >> 2, rq = wid & 3;
  const int r0g = b * 64 + rq * 16;

  {
    const int r = tid >> 5, c = tid & 31;
    *reinterpret_cast<float4*>(&Qs[r * 132 + c * 4]) =
        *reinterpret_cast<const float4*>(&ws[OFF_Q + (r0g + r) * 128 + c * 4]);
  }
  st64r<512>(tid, ws + OFF_ET + b * 8192, Bs, 128);
  __syncthreads();
  float sc[2] = {};
  score_full(tid, Qs, Bs, sc);
  softmax_write(tid, sc, Wp, out + BNN + b * 4096 + rq * 1024);
  __syncthreads();
  // av_pre = w_pre @ e[b] (K=64)
  st128<512>(tid, ws + OFF_E + b * 8192, Bs, 64);
  __syncthreads();
  {
    float a[4] = {};
    g1(tid, Wp, 68, Bs, 64, a);
    epi<false, false>(tid, a, AV, 132, nullptr);
  }
  __syncthreads();
  // se = lrelu(av_pre @ Wse^T + b_se) (K=128)
  st128<512>(tid, ws + OFF_WSET, Bs, 64);
  __syncthreads();
  float as[4] = {};
  g1(tid, AV, 132, Bs, 64, as);
  __syncthreads();
  st128<512>(tid, ws + OFF_WSET + 8192, Bs, 64);
  __syncthreads();
  g1(tid, AV + 64, 132, Bs, 64, as);
  {
    const int c0 = (tid & 31) * 4, rg = tid >> 5;
    float t[4];
#pragma unroll
    for (int i = 0; i < 4; ++i) {
      float x = as[i] + b_se[c0 + i];
      t[i] = (x > 0.f) ? x : NSLOPE * x;
    }
    float4 v; v.x = t[0]; v.y = t[1]; v.z = t[2]; v.w = t[3];
    *reinterpret_cast<float4*>(&SEr[rg * 132 + c0]) = v;
  }
  __syncthreads();
  wrT(tid, SEr, ws + OFF_SET + b * 8192, rq);
  st128<512>(tid, ws + OFF_M, Bs, 64);
  __syncthreads();
  // f2 = se @ M (K=128) -> ws.Q
  float af[4] = {};
  g1(tid, SEr, 132, Bs, 64, af);
  __syncthreads();
  st128<512>(tid, ws + OFF_M + 8192, Bs, 64);
  __syncthreads();
  g1(tid, SEr + 64, 132, Bs, 64, af);
  epi<false, false>(tid, af, ws + OFF_Q + r0g * 128, 128, nullptr);
}

// P4: grid 256 (swizzled), 512 thr, 16 rows. score2 -> w ; h_base = w @ ha ; head.
__global__ __launch_bounds__(512) void P4(const float* __restrict__ Wf2g,
                                          float* __restrict__ ws,
                                          float* __restrict__ out) {
  __shared__ float Qs[16 * 132];
  __shared__ float Bs[8704];
  __shared__ float Wp[16 * 68], Hb[16 * 66];
  __shared__ float Hd[64 * 69];
  __shared__ float Wf2s[64];
  const int tid = threadIdx.x;
  const int wid = ((blockIdx.x & 7) << 5) | (blockIdx.x >> 3);
  const int b = wid >> 2, rq = wid & 3;
  const int r0g = b * 64 + rq * 16;

  for (int idx = tid; idx < 4096; idx += 512)
    Hd[(idx >> 6) * 69 + (idx & 63)] = ws[OFF_HD + b * 4096 + idx];
  if (tid < 64) Wf2s[tid] = Wf2g[tid];
  {
    const int r = tid >> 5, c = tid & 31;
    *reinterpret_cast<float4*>(&Qs[r * 132 + c * 4]) =
        *reinterpret_cast<const float4*>(&ws[OFF_Q + (r0g + r) * 128 + c * 4]);
  }
  st64r<512>(tid, ws + OFF_SET + b * 8192, Bs, 128);
  __syncthreads();
  float sc[2] = {};
  score_full(tid, Qs, Bs, sc);
  softmax_write(tid, sc, Wp, out + 2 * BNN + b * 4096 + rq * 1024);
  __syncthreads();
  // h_base = w @ ha[b] (K=64)
  st64r<512>(tid, ws + OFF_HA + b * 4096, Bs, 64);
  __syncthreads();
  float ah[2] = {};
  gH(tid, Wp, 68, Bs, 64, ah);
  {
    const int c0 = (tid & 31) * 2, rg = tid >> 5;
    float2 v; v.x = ah[0]; v.y = ah[1];
    *reinterpret_cast<float2*>(&Hb[rg * 66 + c0]) = v;
  }
  __syncthreads();
  // head: value[i][j] = sum_f lrelu(Hb[i,f] + w[i,j]*Hd[j,f]) * Wf2[f]
  const int j = tid & 63, iw = tid >> 6;
  float wv[2], a2[2] = {0.f, 0.f};
#pragma unroll
  for (int r = 0; r < 2; ++r) wv[r] = Wp[(iw * 2 + r) * 68 + j];
  for (int f = 0; f < 64; ++f) {
    const float hdv = Hd[j * 69 + f];
    const float wf = Wf2s[f];
#pragma unroll
    for (int r = 0; r < 2; ++r) {
      float t = Hb[(iw * 2 + r) * 66 + f] + wv[r] * hdv;
      t = (t > 0.f) ? t : NSLOPE * t;
      a2[r] += t * wf;
    }
  }
#pragma unroll
  for (int r = 0; r < 2; ++r)
    out[(r0g + iw * 2 + r) * 64 + j] = a2[r];
}

extern "C" void kernel_launch(void* const* d_in, const int* in_sizes, int n_in,
                              void* d_out, int out_size, void* d_ws, size_t ws_size,
                              hipStream_t stream) {
  const float* states   = (const float*)d_in[0];
  const float* policies = (const float*)d_in[1];
  const float* actions  = (const float*)d_in[2];
  const float* W_se_pre = (const float*)d_in[3];
  const float* b_se_pre = (const float*)d_in[4];
  const float* W_key    = (const float*)d_in[5];
  const float* W_query  = (const float*)d_in[6];
  const float* W_se     = (const float*)d_in[7];
  const float* b_se     = (const float*)d_in[8];
  const float* W_sap    = (const float*)d_in[9];
  const float* b_sap    = (const float*)d_in[10];
  const float* W_av     = (const float*)d_in[11];
  const float* W_f1     = (const float*)d_in[12];
  const float* W_f2     = (const float*)d_in[13];
  float* out = (float*)d_out;
  float* ws  = (float*)d_ws;

  WPREP<<<dim3(128), dim3(512), 0, stream>>>(
      W_se_pre, W_query, W_key, W_se, W_sap, W_av, W_f1, ws);
  P1<<<dim3(256), dim3(512), 0, stream>>>(states, policies, actions, b_sap, b_se_pre, ws);
  P3<<<dim3(256), dim3(512), 0, stream>>>(b_se, ws, out);
  P4<<<dim3(256), dim3(512), 0, stream>>>(W_f2, ws, out);
}